// Round 7
// baseline (231.471 us; speedup 1.0000x reference)
//
#include <hip/hip_runtime.h>
#include <stdint.h>

// ---------------- problem constants ----------------
#define BATCH  8
#define SEQ    1025
#define DMODEL 768
#define NHEAD  12
#define HDIM   64
#define MTOT   (BATCH * SEQ)   // 8200 tokens
#define MPAD   8320            // 65 * 128
#define SPAD   1056            // 33 * 32 (padded key length)
#define BHTOT  (BATCH * NHEAD) // 96
#define QT32   33              // ceil(1025/32) q-tiles of 32
#define QKSCALE 0.18033688011112042f   // 0.125 * log2(e) -> exp2-domain softmax

typedef __bf16 bf16x8 __attribute__((ext_vector_type(8)));
typedef __bf16 bf16x4 __attribute__((ext_vector_type(4)));
typedef float  f32x4  __attribute__((ext_vector_type(4)));
typedef float  f32x16 __attribute__((ext_vector_type(16)));

#if __has_builtin(__builtin_amdgcn_exp2f)
#define EXP2F __builtin_amdgcn_exp2f
#else
#define EXP2F exp2f
#endif

// ---------------- workspace layout (bytes) ----------------
constexpr size_t XB_OFF  = 0;
constexpr size_t XB_SZ   = (size_t)MPAD * DMODEL * 2;
constexpr size_t W_SZ    = (size_t)DMODEL * DMODEL * 2;
constexpr size_t WQB_OFF = XB_OFF + XB_SZ;
constexpr size_t WKB_OFF = WQB_OFF + W_SZ;
constexpr size_t WVB_OFF = WKB_OFF + W_SZ;
constexpr size_t WPB_OFF = WVB_OFF + W_SZ;
constexpr size_t QB_OFF  = WPB_OFF + W_SZ;
constexpr size_t QB_SZ   = (size_t)BHTOT * SEQ * HDIM * 2;
constexpr size_t KB_OFF  = QB_OFF + QB_SZ;
constexpr size_t VT_OFF  = KB_OFF + QB_SZ;
constexpr size_t VT_SZ   = (size_t)BHTOT * HDIM * SPAD * 2;
constexpr size_t AO_OFF  = XB_OFF;                          // alias: xb consumed before attn writes
constexpr size_t WS_NEEDED = VT_OFF + VT_SZ;

// ---------------- helpers ----------------
__device__ __forceinline__ void async16(const void* g, void* l) {
  __builtin_amdgcn_global_load_lds((__attribute__((address_space(1))) void*)g,
                                   (__attribute__((address_space(3))) void*)l,
                                   16, 0, 0);
}

// pack two f32 -> bf16x2 dword (lo = first arg); compiler emits cvt_pk.
__device__ __forceinline__ unsigned pkbf(float lo, float hi) {
  __bf16 l = (__bf16)lo, h = (__bf16)hi;
  unsigned short lb = __builtin_bit_cast(unsigned short, l);
  unsigned short hb = __builtin_bit_cast(unsigned short, h);
  return ((unsigned)hb << 16) | (unsigned)lb;
}
__device__ __forceinline__ unsigned shfl32u(unsigned x) {   // partner half's value
  return (unsigned)__shfl_xor((int)x, 32, 64);
}
__device__ __forceinline__ float pairmax(float x) {  // max(own, lane^32)
  return fmaxf(x, __shfl_xor(x, 32, 64));
}
__device__ __forceinline__ float pairsum(float x) {  // own + lane^32
  return x + __shfl_xor(x, 32, 64);
}

// balanced trees (fp not reassociable by compiler without fast-math)
__device__ __forceinline__ float tree_max16(const f32x16& s) {
  float a0 = fmaxf(s[0], s[1]),   a1 = fmaxf(s[2], s[3]);
  float a2 = fmaxf(s[4], s[5]),   a3 = fmaxf(s[6], s[7]);
  float a4 = fmaxf(s[8], s[9]),   a5 = fmaxf(s[10], s[11]);
  float a6 = fmaxf(s[12], s[13]), a7 = fmaxf(s[14], s[15]);
  float b0 = fmaxf(a0, a1), b1 = fmaxf(a2, a3);
  float b2 = fmaxf(a4, a5), b3 = fmaxf(a6, a7);
  return fmaxf(fmaxf(b0, b1), fmaxf(b2, b3));
}
__device__ __forceinline__ float tree_sum16(const f32x16& s) {
  float a0 = s[0] + s[1],   a1 = s[2] + s[3];
  float a2 = s[4] + s[5],   a3 = s[6] + s[7];
  float a4 = s[8] + s[9],   a5 = s[10] + s[11];
  float a6 = s[12] + s[13], a7 = s[14] + s[15];
  float b0 = a0 + a1, b1 = a2 + a3, b2 = a4 + a5, b3 = a6 + a7;
  return (b0 + b1) + (b2 + b3);
}

// ---------------- fp32 -> bf16 conversion (zero-fills dst beyond n_src) ----------------
__global__ void __launch_bounds__(256)
convert_f32_bf16(const float* __restrict__ src, __bf16* __restrict__ dst,
                 int n_src, int n_dst) {
  int idx = (blockIdx.x * 256 + threadIdx.x) * 4;
  if (idx >= n_dst) return;
  bf16x4 o;
  if (idx + 3 < n_src) {
    float4 v = *(const float4*)&src[idx];
    o[0] = (__bf16)v.x; o[1] = (__bf16)v.y; o[2] = (__bf16)v.z; o[3] = (__bf16)v.w;
  } else {
    #pragma unroll
    for (int t = 0; t < 4; ++t) {
      int k = idx + t;
      o[t] = (k < n_src) ? (__bf16)src[k] : (__bf16)0.f;
    }
  }
  *(bf16x4*)&dst[idx] = o;
}

// 4 weight matrices in one launch; dst regions are contiguous (WQB..WPB).
__global__ void __launch_bounds__(256)
convert_w4(const float* __restrict__ w0, const float* __restrict__ w1,
           const float* __restrict__ w2, const float* __restrict__ w3,
           __bf16* __restrict__ dst) {
  const int which = blockIdx.y;
  const float* src = (which == 0) ? w0 : (which == 1) ? w1 : (which == 2) ? w2 : w3;
  __bf16* d = dst + (size_t)which * DMODEL * DMODEL;
  int idx = (blockIdx.x * 256 + threadIdx.x) * 4;
  if (idx >= DMODEL * DMODEL) return;
  float4 v = *(const float4*)&src[idx];
  bf16x4 o;
  o[0] = (__bf16)v.x; o[1] = (__bf16)v.y; o[2] = (__bf16)v.z; o[3] = (__bf16)v.w;
  *(bf16x4*)&d[idx] = o;
}

// ---------------- shared 128x128 GEMM core: C = A @ W^T ----------------
__device__ __forceinline__ void gemm_core(const __bf16* __restrict__ A,
                                          const __bf16* __restrict__ W,
                                          __bf16* As, __bf16* Bs,
                                          int m0, int n0, f32x4 acc[4][4]) {
  const int tid  = threadIdx.x;
  const int lane = tid & 63;
  const int wave = tid >> 6;
  const int wm = wave >> 1, wn = wave & 1;
  const int l15 = lane & 15, lg = lane >> 4;

  for (int kt = 0; kt < DMODEL; kt += 64) {
    __syncthreads();
    #pragma unroll
    for (int i = 0; i < 4; ++i) {
      int e = (i * 256 + tid) * 8;
      int r = e >> 6, c = e & 63;
      async16(A + (size_t)(m0 + r) * DMODEL + kt + c, As + e);
      async16(W + (size_t)(n0 + r) * DMODEL + kt + c, Bs + e);
    }
    __syncthreads();
    #pragma unroll
    for (int kk = 0; kk < 2; ++kk) {
      bf16x8 af[4], bfr[4];
      #pragma unroll
      for (int i = 0; i < 4; ++i)
        af[i] = *(const bf16x8*)&As[(wm * 64 + i * 16 + l15) * 64 + kk * 32 + lg * 8];
      #pragma unroll
      for (int j = 0; j < 4; ++j)
        bfr[j] = *(const bf16x8*)&Bs[(wn * 64 + j * 16 + l15) * 64 + kk * 32 + lg * 8];
      #pragma unroll
      for (int i = 0; i < 4; ++i)
        #pragma unroll
        for (int j = 0; j < 4; ++j)
          acc[i][j] = __builtin_amdgcn_mfma_f32_16x16x32_bf16(af[i], bfr[j], acc[i][j], 0, 0, 0);
    }
  }
}

// ---------------- QKV projection ----------------
__global__ void __launch_bounds__(256)
gemm_qkv_kernel(const __bf16* __restrict__ xb,
                const __bf16* __restrict__ wqb, const __bf16* __restrict__ wkb,
                const __bf16* __restrict__ wvb,
                const float* __restrict__ bq, const float* __restrict__ bk,
                const float* __restrict__ bv,
                __bf16* __restrict__ qb, __bf16* __restrict__ kb,
                __bf16* __restrict__ vtb) {
  __shared__ __bf16 As[128 * 64];
  __shared__ __bf16 Bs[128 * 64];
  const int mode = blockIdx.z;
  const __bf16* W  = (mode == 0) ? wqb : (mode == 1) ? wkb : wvb;
  const float* bias = (mode == 0) ? bq : (mode == 1) ? bk : bv;
  const int m0 = blockIdx.x * 128, n0 = blockIdx.y * 128;

  f32x4 acc[4][4];
  #pragma unroll
  for (int i = 0; i < 4; ++i)
    #pragma unroll
    for (int j = 0; j < 4; ++j) acc[i][j] = (f32x4){0.f, 0.f, 0.f, 0.f};

  gemm_core(xb, W, As, Bs, m0, n0, acc);

  const int lane = threadIdx.x & 63;
  const int wave = threadIdx.x >> 6;
  const int wm = wave >> 1, wn = wave & 1;
  const int l15 = lane & 15, lg = lane >> 4;
  #pragma unroll
  for (int i = 0; i < 4; ++i) {
    #pragma unroll
    for (int j = 0; j < 4; ++j) {
      const int ncol = n0 + wn * 64 + j * 16 + l15;
      const float bb = bias[ncol];
      const int h = ncol >> 6, hd = ncol & 63;
      #pragma unroll
      for (int r = 0; r < 4; ++r) {
        const int mrow = m0 + wm * 64 + i * 16 + lg * 4 + r;
        if (mrow < MTOT) {
          float val = acc[i][j][r] + bb;
          const int b = mrow / SEQ;
          const int s = mrow - b * SEQ;
          const int bh = b * NHEAD + h;
          if (mode == 2)
            vtb[((size_t)bh * HDIM + hd) * SPAD + s] = (__bf16)val;
          else if (mode == 0)
            qb[((size_t)bh * SEQ + s) * HDIM + hd] = (__bf16)(val * QKSCALE);
          else
            kb[((size_t)bh * SEQ + s) * HDIM + hd] = (__bf16)val;
        }
      }
    }
  }
}

// ---------------- output projection ----------------
__global__ void __launch_bounds__(256)
gemm_proj_kernel(const __bf16* __restrict__ ab, const __bf16* __restrict__ wpb,
                 const float* __restrict__ bp, float* __restrict__ out) {
  __shared__ __bf16 As[128 * 64];
  __shared__ __bf16 Bs[128 * 64];
  const int m0 = blockIdx.x * 128, n0 = blockIdx.y * 128;

  f32x4 acc[4][4];
  #pragma unroll
  for (int i = 0; i < 4; ++i)
    #pragma unroll
    for (int j = 0; j < 4; ++j) acc[i][j] = (f32x4){0.f, 0.f, 0.f, 0.f};

  gemm_core(ab, wpb, As, Bs, m0, n0, acc);

  const int lane = threadIdx.x & 63;
  const int wave = threadIdx.x >> 6;
  const int wm = wave >> 1, wn = wave & 1;
  const int l15 = lane & 15, lg = lane >> 4;
  #pragma unroll
  for (int i = 0; i < 4; ++i) {
    #pragma unroll
    for (int j = 0; j < 4; ++j) {
      const int ncol = n0 + wn * 64 + j * 16 + l15;
      const float bb = bp[ncol];
      #pragma unroll
      for (int r = 0; r < 4; ++r) {
        const int mrow = m0 + wm * 64 + i * 16 + lg * 4 + r;
        if (mrow < MTOT) out[(size_t)mrow * DMODEL + ncol] = acc[i][j][r] + bb;
      }
    }
  }
}

// ---------------- flash attention: split-K 2-wave blocks, K-pair ILP, XCD swizzle ----
// Block = 128 threads = 2 waves, one (bh, 32-row q-tile). Wave w handles K-tiles
// t = w, w+2, ... (processed in PAIRS for ILP) with private online-softmax state;
// exact merge via LDS at end. Lane owns q = q0 + (lane&31).
// Scores: D[key][q] = mfma(K, Q). PV: out^T[d][q] = mfma(V^T, P).
// C/D: col = lane&31, row = crow(r,hi) = (r&3)+8*(r>>2)+4*hi.

// build the two B-fragments (32 keys) for one score vector
__device__ __forceinline__ void build_pa(const f32x16& s, int hi, bf16x8 pa[2]) {
  #pragma unroll
  for (int sl2 = 0; sl2 < 2; ++sl2) {
    const int off = sl2 * 8;
    unsigned w0 = pkbf(s[off + 0], s[off + 1]);
    unsigned w1 = pkbf(s[off + 2], s[off + 3]);
    unsigned w2 = pkbf(s[off + 4], s[off + 5]);
    unsigned w3 = pkbf(s[off + 6], s[off + 7]);
    unsigned p0 = shfl32u(w0), p1 = shfl32u(w1);
    unsigned p2 = shfl32u(w2), p3 = shfl32u(w3);
    unsigned pw[4];
    pw[0] = hi ? p2 : w0;
    pw[1] = hi ? p3 : w1;
    pw[2] = hi ? w2 : p0;
    pw[3] = hi ? w3 : p1;
    __builtin_memcpy(&pa[sl2], pw, 16);
  }
}

// two K-tiles (64 keys) per call: independent score chains, one softmax update
__device__ __forceinline__ void attn_tile2(int k0a, const __bf16* __restrict__ Kp,
                                           const __bf16* __restrict__ Vp,
                                           const bf16x8 (&qf)[4], int l31, int hi,
                                           float& mrun, float& lrun,
                                           f32x16& o0, f32x16& o1) {
  const int k0b = k0a + 64;
  const __bf16* kba = Kp + (size_t)(k0a + l31) * HDIM + hi * 8;
  const __bf16* kbb = Kp + (size_t)(k0b + l31) * HDIM + hi * 8;

  f32x16 sa, sb;
  #pragma unroll
  for (int r = 0; r < 16; ++r) { sa[r] = 0.f; sb[r] = 0.f; }

  __builtin_amdgcn_s_setprio(1);
  #pragma unroll
  for (int sl = 0; sl < 4; ++sl) {
    bf16x8 kfa = *(const bf16x8*)(kba + sl * 16);
    bf16x8 kfb = *(const bf16x8*)(kbb + sl * 16);
    sa = __builtin_amdgcn_mfma_f32_32x32x16_bf16(kfa, qf[sl], sa, 0, 0, 0);
    sb = __builtin_amdgcn_mfma_f32_32x32x16_bf16(kfb, qf[sl], sb, 0, 0, 0);
  }
  __builtin_amdgcn_s_setprio(0);

  // V fragments issued now; softmax (~300 cyc) covers their latency
  const __bf16* vba = Vp + (size_t)l31 * SPAD + k0a + hi * 8;
  const __bf16* vbb = Vp + (size_t)l31 * SPAD + k0b + hi * 8;
  bf16x8 vfa00 = *(const bf16x8*)(vba);
  bf16x8 vfa01 = *(const bf16x8*)(vba + 16);
  bf16x8 vfa10 = *(const bf16x8*)(vba + (size_t)32 * SPAD);
  bf16x8 vfa11 = *(const bf16x8*)(vba + (size_t)32 * SPAD + 16);
  bf16x8 vfb00 = *(const bf16x8*)(vbb);
  bf16x8 vfb01 = *(const bf16x8*)(vbb + 16);
  bf16x8 vfb10 = *(const bf16x8*)(vbb + (size_t)32 * SPAD);
  bf16x8 vfb11 = *(const bf16x8*)(vbb + (size_t)32 * SPAD + 16);

  // merged online-softmax over 64 keys
  const float mloc = pairmax(fmaxf(tree_max16(sa), tree_max16(sb)));

  if (!__all(mloc - mrun <= 8.f)) {   // defer-max (T13)
    const float mnew = fmaxf(mrun, mloc);
    const float corr = EXP2F(mrun - mnew);
    lrun *= corr;
    #pragma unroll
    for (int r = 0; r < 16; ++r) { o0[r] *= corr; o1[r] *= corr; }
    mrun = mnew;
  }

  #pragma unroll
  for (int r = 0; r < 16; ++r) { sa[r] = EXP2F(sa[r] - mrun); sb[r] = EXP2F(sb[r] - mrun); }
  lrun += pairsum(tree_sum16(sa) + tree_sum16(sb));

  bf16x8 paa[2], pab[2];
  build_pa(sa, hi, paa);
  build_pa(sb, hi, pab);

  __builtin_amdgcn_s_setprio(1);
  o0 = __builtin_amdgcn_mfma_f32_32x32x16_bf16(vfa00, paa[0], o0, 0, 0, 0);
  o1 = __builtin_amdgcn_mfma_f32_32x32x16_bf16(vfa10, paa[0], o1, 0, 0, 0);
  o0 = __builtin_amdgcn_mfma_f32_32x32x16_bf16(vfa01, paa[1], o0, 0, 0, 0);
  o1 = __builtin_amdgcn_mfma_f32_32x32x16_bf16(vfa11, paa[1], o1, 0, 0, 0);
  o0 = __builtin_amdgcn_mfma_f32_32x32x16_bf16(vfb00, pab[0], o0, 0, 0, 0);
  o1 = __builtin_amdgcn_mfma_f32_32x32x16_bf16(vfb10, pab[0], o1, 0, 0, 0);
  o0 = __builtin_amdgcn_mfma_f32_32x32x16_bf16(vfb01, pab[1], o0, 0, 0, 0);
  o1 = __builtin_amdgcn_mfma_f32_32x32x16_bf16(vfb11, pab[1], o1, 0, 0, 0);
  __builtin_amdgcn_s_setprio(0);
}

// single-tile path, used only for the masked tail tile (t=32, 1 valid key)
template<bool MASK>
__device__ __forceinline__ void attn_tile(int k0, const __bf16* __restrict__ Kp,
                                          const __bf16* __restrict__ Vp,
                                          const bf16x8 (&qf)[4], int l31, int hi,
                                          float& mrun, float& lrun,
                                          f32x16& o0, f32x16& o1) {
  const __bf16* vb = Vp + (size_t)l31 * SPAD + k0 + hi * 8;
  bf16x8 vf00 = *(const bf16x8*)(vb);
  bf16x8 vf01 = *(const bf16x8*)(vb + 16);
  bf16x8 vf10 = *(const bf16x8*)(vb + (size_t)32 * SPAD);
  bf16x8 vf11 = *(const bf16x8*)(vb + (size_t)32 * SPAD + 16);

  int krow = k0 + l31;
  if (MASK) krow = krow < SEQ ? krow : SEQ - 1;
  const __bf16* kbase = Kp + (size_t)krow * HDIM + hi * 8;

  f32x16 s;
  #pragma unroll
  for (int r = 0; r < 16; ++r) s[r] = 0.f;
  #pragma unroll
  for (int sl = 0; sl < 4; ++sl) {
    bf16x8 kf = *(const bf16x8*)(kbase + sl * 16);
    s = __builtin_amdgcn_mfma_f32_32x32x16_bf16(kf, qf[sl], s, 0, 0, 0);
  }
  if (MASK) {  // only key k0 (crow==0: r==0 && hi==0) is valid in the tail tile
    #pragma unroll
    for (int r = 1; r < 16; ++r) s[r] = -1e30f;
    if (hi) s[0] = -1e30f;
  }

  const float mloc = pairmax(tree_max16(s));
  if (!__all(mloc - mrun <= 8.f)) {
    const float mnew = fmaxf(mrun, mloc);
    const float corr = EXP2F(mrun - mnew);
    lrun *= corr;
    #pragma unroll
    for (int r = 0; r < 16; ++r) { o0[r] *= corr; o1[r] *= corr; }
    mrun = mnew;
  }

  #pragma unroll
  for (int r = 0; r < 16; ++r) s[r] = EXP2F(s[r] - mrun);
  lrun += pairsum(tree_sum16(s));

  bf16x8 pa[2];
  build_pa(s, hi, pa);

  o0 = __builtin_amdgcn_mfma_f32_32x32x16_bf16(vf00, pa[0], o0, 0, 0, 0);
  o0 = __builtin_amdgcn_mfma_f32_32x32x16_bf16(vf01, pa[1], o0, 0, 0, 0);
  o1 = __builtin_amdgcn_mfma_f32_32x32x16_bf16(vf10, pa[0], o1, 0, 0, 0);
  o1 = __builtin_amdgcn_mfma_f32_32x32x16_bf16(vf11, pa[1], o1, 0, 0, 0);
}

__global__ void __launch_bounds__(128)
attn_kernel(const __bf16* __restrict__ qb, const __bf16* __restrict__ kb,
            const __bf16* __restrict__ vtb, __bf16* __restrict__ ao) {
  __shared__ float obuf[32][64];   // [reg r][lane] -> conflict-free both directions
  __shared__ float mbuf[64], lbuf[64];

  const int tid  = threadIdx.x;
  const int wid  = tid >> 6;
  const int lane = tid & 63;
  const int l31 = lane & 31, hi = (lane >> 5) & 1;

  // XCD-aware swizzle (T1): dispatch assigns XCD = blockIdx.x % 8. Map so all
  // 33 q-tile blocks of a bh land on ONE XCD: per-XCD K/V set = 12bh*266KB = 3.2MB <= 4MB L2.
  // Bijective: 3168 = 8 * 396, 396 = 12 * 33.
  const int bid = blockIdx.x;
  const int xcd = bid & 7;
  const int ixd = bid >> 3;                  // 0..395
  const int bh  = xcd * (BHTOT / 8) + ixd / QT32;
  const int qt  = ixd % QT32;

  const __bf16* Qp = qb + (size_t)bh * SEQ * HDIM;
  const __bf16* Kp = kb + (size_t)bh * SEQ * HDIM;
  const __bf16* Vp = vtb + (size_t)bh * HDIM * SPAD;

  const int qidx = qt * 32 + l31;
  const int qc = qidx < SEQ ? qidx : SEQ - 1;
  bf16x8 qf[4];
  #pragma unroll
  for (int sl = 0; sl < 4; ++sl)
    qf[sl] = *(const bf16x8*)&Qp[(size_t)qc * HDIM + sl * 16 + hi * 8];

  f32x16 o0, o1;
  #pragma unroll
  for (int r = 0; r < 16; ++r) { o0[r] = 0.f; o1[r] = 0.f; }
  float mrun = -1e30f, lrun = 0.f;

  // wave `wid` owns tiles t = wid + 2u (u=0..15), processed as 8 pairs:
  // pair p = tiles (wid+4p, wid+4p+2) -> k0 = wid*32 + p*128, k0b = k0 + 64.
  for (int p = 0; p < 8; ++p)
    attn_tile2(wid * 32 + p * 128, Kp, Vp, qf, l31, hi, mrun, lrun, o0, o1);
  // tail tile t=32 (1 valid key) -> wave 0
  if (wid == 0)
    attn_tile<true>(1024, Kp, Vp, qf, l31, hi, mrun, lrun, o0, o1);

  // ---- merge the two waves' online-softmax states ----
  if (wid == 1) {
    mbuf[lane] = mrun;
    lbuf[lane] = lrun;
    #pragma unroll
    for (int r = 0; r < 16; ++r) { obuf[r][lane] = o0[r]; obuf[16 + r][lane] = o1[r]; }
  }
  __syncthreads();
  if (wid != 0) return;

  const float m1 = mbuf[lane], l1 = lbuf[lane];
  const float M  = fmaxf(mrun, m1);
  const float c0 = EXP2F(mrun - M);
  const float c1 = EXP2F(m1 - M);
  const float inv = 1.f / (lrun * c0 + l1 * c1);

  const int b = bh / NHEAD, h = bh % NHEAD;
  if (qidx < SEQ) {
    __bf16* base = ao + ((size_t)b * SEQ + qidx) * DMODEL + h * HDIM + hi * 4;
    #pragma unroll
    for (int t = 0; t < 2; ++t) {
      const f32x16& o = t ? o1 : o0;
      #pragma unroll
      for (int g = 0; g < 4; ++g) {
        bf16x4 w;
        #pragma unroll
        for (int u = 0; u < 4; ++u) {
          const int r = g * 4 + u;
          const float merged = o[r] * c0 + obuf[t * 16 + r][lane] * c1;
          w[u] = (__bf16)(merged * inv);
        }
        *(bf16x4*)(base + t * 32 + g * 8) = w;
      }
    }
  }
}

// ---------------- launcher ----------------
extern "C" void kernel_launch(void* const* d_in, const int* in_sizes, int n_in,
                              void* d_out, int out_size, void* d_ws, size_t ws_size,
                              hipStream_t stream) {
  const float* x  = (const float*)d_in[0];
  const float* Wk = (const float*)d_in[1];
  const float* bk = (const float*)d_in[2];
  const float* Wq = (const float*)d_in[3];
  const float* bq = (const float*)d_in[4];
  const float* Wv = (const float*)d_in[5];
  const float* bv = (const float*)d_in[6];
  const float* Wp = (const float*)d_in[7];
  const float* bp = (const float*)d_in[8];
  float* out = (float*)d_out;

  if (ws_size < WS_NEEDED) return;

  char* ws = (char*)d_ws;
  __bf16* xb  = (__bf16*)(ws + XB_OFF);
  __bf16* wqb = (__bf16*)(ws + WQB_OFF);
  __bf16* wkb = (__bf16*)(ws + WKB_OFF);
  __bf16* wvb = (__bf16*)(ws + WVB_OFF);
  __bf16* wpb = (__bf16*)(ws + WPB_OFF);
  __bf16* qb  = (__bf16*)(ws + QB_OFF);
  __bf16* kb  = (__bf16*)(ws + KB_OFF);
  __bf16* vtb = (__bf16*)(ws + VT_OFF);
  __bf16* ab  = (__bf16*)(ws + AO_OFF);  // aliases xb

  // zero V^T (incl. padded tail columns 1025..1055 -> exact 0 * 0 in PV, no NaN)
  hipMemsetAsync(vtb, 0, VT_SZ, stream);

  {
    const int n_src = MTOT * DMODEL, n_dst = MPAD * DMODEL;
    convert_f32_bf16<<<dim3((n_dst / 4 + 255) / 256), dim3(256), 0, stream>>>(x, xb, n_src, n_dst);
    const int nw = DMODEL * DMODEL;
    convert_w4<<<dim3((nw / 4 + 255) / 256, 4), dim3(256), 0, stream>>>(Wq, Wk, Wv, Wp, wqb);
  }

  gemm_qkv_kernel<<<dim3(MPAD / 128, DMODEL / 128, 3), dim3(256), 0, stream>>>(
      xb, wqb, wkb, wvb, bq, bk, bv, qb, kb, vtb);

  attn_kernel<<<dim3(BHTOT * QT32), dim3(128), 0, stream>>>(qb, kb, vtb, ab);

  gemm_proj_kernel<<<dim3(MPAD / 128, DMODEL / 128), dim3(256), 0, stream>>>(
      ab, wpb, bp, out);
}

// Round 8
// 194.156 us; speedup vs baseline: 1.1922x; 1.1922x over previous
//
#include <hip/hip_runtime.h>
#include <stdint.h>

// ---------------- problem constants ----------------
#define BATCH  8
#define SEQ    1025
#define DMODEL 768
#define NHEAD  12
#define HDIM   64
#define MTOT   (BATCH * SEQ)   // 8200 tokens
#define MPAD   8320            // 65 * 128
#define SPAD   1056            // 33 * 32 (padded key length, zero-filled)
#define BHTOT  (BATCH * NHEAD) // 96
#define QT32   33              // ceil(1025/32) q-tiles of 32
#define NTILE  17              // ceil(1025/64) KV tiles of 64
#define QKSCALE 0.18033688011112042f   // 0.125 * log2(e) -> exp2-domain softmax

typedef __bf16 bf16x8 __attribute__((ext_vector_type(8)));
typedef __bf16 bf16x4 __attribute__((ext_vector_type(4)));
typedef float  f32x4  __attribute__((ext_vector_type(4)));
typedef float  f32x16 __attribute__((ext_vector_type(16)));

#if __has_builtin(__builtin_amdgcn_exp2f)
#define EXP2F __builtin_amdgcn_exp2f
#else
#define EXP2F exp2f
#endif

// ---------------- workspace layout (bytes) ----------------
constexpr size_t XB_OFF  = 0;
constexpr size_t XB_SZ   = (size_t)MPAD * DMODEL * 2;
constexpr size_t W_SZ    = (size_t)DMODEL * DMODEL * 2;
constexpr size_t WQB_OFF = XB_OFF + XB_SZ;
constexpr size_t WKB_OFF = WQB_OFF + W_SZ;
constexpr size_t WVB_OFF = WKB_OFF + W_SZ;
constexpr size_t WPB_OFF = WVB_OFF + W_SZ;
constexpr size_t QB_OFF  = WPB_OFF + W_SZ;
constexpr size_t QB_SZ   = (size_t)BHTOT * SEQ * HDIM * 2;
constexpr size_t KB_OFF  = QB_OFF + QB_SZ;
constexpr size_t VT_OFF  = KB_OFF + QB_SZ;                  // K-tail overrun lands here (zeros)
constexpr size_t VT_SZ   = (size_t)BHTOT * HDIM * SPAD * 2;
constexpr size_t AO_OFF  = XB_OFF;                          // alias: xb consumed before attn writes
constexpr size_t WS_NEEDED = VT_OFF + VT_SZ;

// ---------------- helpers ----------------
__device__ __forceinline__ void async16(const void* g, void* l) {
  __builtin_amdgcn_global_load_lds((__attribute__((address_space(1))) void*)g,
                                   (__attribute__((address_space(3))) void*)l,
                                   16, 0, 0);
}

// pack two f32 -> bf16x2 dword (lo = first arg); compiler emits cvt_pk.
__device__ __forceinline__ unsigned pkbf(float lo, float hi) {
  __bf16 l = (__bf16)lo, h = (__bf16)hi;
  unsigned short lb = __builtin_bit_cast(unsigned short, l);
  unsigned short hb = __builtin_bit_cast(unsigned short, h);
  return ((unsigned)hb << 16) | (unsigned)lb;
}
__device__ __forceinline__ unsigned shfl32u(unsigned x) {   // partner half's value
  return (unsigned)__shfl_xor((int)x, 32, 64);
}
__device__ __forceinline__ float pairmax(float x) {  // max(own, lane^32)
  return fmaxf(x, __shfl_xor(x, 32, 64));
}
__device__ __forceinline__ float pairsum(float x) {  // own + lane^32
  return x + __shfl_xor(x, 32, 64);
}

// balanced trees (fp not reassociable by compiler without fast-math)
__device__ __forceinline__ float tree_max16(const f32x16& s) {
  float a0 = fmaxf(s[0], s[1]),   a1 = fmaxf(s[2], s[3]);
  float a2 = fmaxf(s[4], s[5]),   a3 = fmaxf(s[6], s[7]);
  float a4 = fmaxf(s[8], s[9]),   a5 = fmaxf(s[10], s[11]);
  float a6 = fmaxf(s[12], s[13]), a7 = fmaxf(s[14], s[15]);
  float b0 = fmaxf(a0, a1), b1 = fmaxf(a2, a3);
  float b2 = fmaxf(a4, a5), b3 = fmaxf(a6, a7);
  return fmaxf(fmaxf(b0, b1), fmaxf(b2, b3));
}
__device__ __forceinline__ float tree_sum16(const f32x16& s) {
  float a0 = s[0] + s[1],   a1 = s[2] + s[3];
  float a2 = s[4] + s[5],   a3 = s[6] + s[7];
  float a4 = s[8] + s[9],   a5 = s[10] + s[11];
  float a6 = s[12] + s[13], a7 = s[14] + s[15];
  float b0 = a0 + a1, b1 = a2 + a3, b2 = a4 + a5, b3 = a6 + a7;
  return (b0 + b1) + (b2 + b3);
}

// ---------------- fp32 -> bf16 conversion (zero-fills dst beyond n_src) ----------------
__global__ void __launch_bounds__(256)
convert_f32_bf16(const float* __restrict__ src, __bf16* __restrict__ dst,
                 int n_src, int n_dst) {
  int idx = (blockIdx.x * 256 + threadIdx.x) * 4;
  if (idx >= n_dst) return;
  bf16x4 o;
  if (idx + 3 < n_src) {
    float4 v = *(const float4*)&src[idx];
    o[0] = (__bf16)v.x; o[1] = (__bf16)v.y; o[2] = (__bf16)v.z; o[3] = (__bf16)v.w;
  } else {
    #pragma unroll
    for (int t = 0; t < 4; ++t) {
      int k = idx + t;
      o[t] = (k < n_src) ? (__bf16)src[k] : (__bf16)0.f;
    }
  }
  *(bf16x4*)&dst[idx] = o;
}

// 4 weight matrices in one launch; dst regions are contiguous (WQB..WPB).
__global__ void __launch_bounds__(256)
convert_w4(const float* __restrict__ w0, const float* __restrict__ w1,
           const float* __restrict__ w2, const float* __restrict__ w3,
           __bf16* __restrict__ dst) {
  const int which = blockIdx.y;
  const float* src = (which == 0) ? w0 : (which == 1) ? w1 : (which == 2) ? w2 : w3;
  __bf16* d = dst + (size_t)which * DMODEL * DMODEL;
  int idx = (blockIdx.x * 256 + threadIdx.x) * 4;
  if (idx >= DMODEL * DMODEL) return;
  float4 v = *(const float4*)&src[idx];
  bf16x4 o;
  o[0] = (__bf16)v.x; o[1] = (__bf16)v.y; o[2] = (__bf16)v.z; o[3] = (__bf16)v.w;
  *(bf16x4*)&d[idx] = o;
}

// ---------------- shared 128x128 GEMM core: C = A @ W^T ----------------
__device__ __forceinline__ void gemm_core(const __bf16* __restrict__ A,
                                          const __bf16* __restrict__ W,
                                          __bf16* As, __bf16* Bs,
                                          int m0, int n0, f32x4 acc[4][4]) {
  const int tid  = threadIdx.x;
  const int lane = tid & 63;
  const int wave = tid >> 6;
  const int wm = wave >> 1, wn = wave & 1;
  const int l15 = lane & 15, lg = lane >> 4;

  for (int kt = 0; kt < DMODEL; kt += 64) {
    __syncthreads();
    #pragma unroll
    for (int i = 0; i < 4; ++i) {
      int e = (i * 256 + tid) * 8;
      int r = e >> 6, c = e & 63;
      async16(A + (size_t)(m0 + r) * DMODEL + kt + c, As + e);
      async16(W + (size_t)(n0 + r) * DMODEL + kt + c, Bs + e);
    }
    __syncthreads();
    #pragma unroll
    for (int kk = 0; kk < 2; ++kk) {
      bf16x8 af[4], bfr[4];
      #pragma unroll
      for (int i = 0; i < 4; ++i)
        af[i] = *(const bf16x8*)&As[(wm * 64 + i * 16 + l15) * 64 + kk * 32 + lg * 8];
      #pragma unroll
      for (int j = 0; j < 4; ++j)
        bfr[j] = *(const bf16x8*)&Bs[(wn * 64 + j * 16 + l15) * 64 + kk * 32 + lg * 8];
      #pragma unroll
      for (int i = 0; i < 4; ++i)
        #pragma unroll
        for (int j = 0; j < 4; ++j)
          acc[i][j] = __builtin_amdgcn_mfma_f32_16x16x32_bf16(af[i], bfr[j], acc[i][j], 0, 0, 0);
    }
  }
}

// ---------------- QKV projection ----------------
__global__ void __launch_bounds__(256)
gemm_qkv_kernel(const __bf16* __restrict__ xb,
                const __bf16* __restrict__ wqb, const __bf16* __restrict__ wkb,
                const __bf16* __restrict__ wvb,
                const float* __restrict__ bq, const float* __restrict__ bk,
                const float* __restrict__ bv,
                __bf16* __restrict__ qb, __bf16* __restrict__ kb,
                __bf16* __restrict__ vtb) {
  __shared__ __bf16 As[128 * 64];
  __shared__ __bf16 Bs[128 * 64];
  const int mode = blockIdx.z;
  const __bf16* W  = (mode == 0) ? wqb : (mode == 1) ? wkb : wvb;
  const float* bias = (mode == 0) ? bq : (mode == 1) ? bk : bv;
  const int m0 = blockIdx.x * 128, n0 = blockIdx.y * 128;

  f32x4 acc[4][4];
  #pragma unroll
  for (int i = 0; i < 4; ++i)
    #pragma unroll
    for (int j = 0; j < 4; ++j) acc[i][j] = (f32x4){0.f, 0.f, 0.f, 0.f};

  gemm_core(xb, W, As, Bs, m0, n0, acc);

  const int lane = threadIdx.x & 63;
  const int wave = threadIdx.x >> 6;
  const int wm = wave >> 1, wn = wave & 1;
  const int l15 = lane & 15, lg = lane >> 4;
  #pragma unroll
  for (int i = 0; i < 4; ++i) {
    #pragma unroll
    for (int j = 0; j < 4; ++j) {
      const int ncol = n0 + wn * 64 + j * 16 + l15;
      const float bb = bias[ncol];
      const int h = ncol >> 6, hd = ncol & 63;
      #pragma unroll
      for (int r = 0; r < 4; ++r) {
        const int mrow = m0 + wm * 64 + i * 16 + lg * 4 + r;
        if (mrow < MTOT) {
          float val = acc[i][j][r] + bb;
          const int b = mrow / SEQ;
          const int s = mrow - b * SEQ;
          const int bh = b * NHEAD + h;
          if (mode == 2)
            vtb[((size_t)bh * HDIM + hd) * SPAD + s] = (__bf16)val;
          else if (mode == 0)
            qb[((size_t)bh * SEQ + s) * HDIM + hd] = (__bf16)(val * QKSCALE);
          else
            kb[((size_t)bh * SEQ + s) * HDIM + hd] = (__bf16)val;
        }
      }
    }
  }
}

// ---------------- output projection ----------------
__global__ void __launch_bounds__(256)
gemm_proj_kernel(const __bf16* __restrict__ ab, const __bf16* __restrict__ wpb,
                 const float* __restrict__ bp, float* __restrict__ out) {
  __shared__ __bf16 As[128 * 64];
  __shared__ __bf16 Bs[128 * 64];
  const int m0 = blockIdx.x * 128, n0 = blockIdx.y * 128;

  f32x4 acc[4][4];
  #pragma unroll
  for (int i = 0; i < 4; ++i)
    #pragma unroll
    for (int j = 0; j < 4; ++j) acc[i][j] = (f32x4){0.f, 0.f, 0.f, 0.f};

  gemm_core(ab, wpb, As, Bs, m0, n0, acc);

  const int lane = threadIdx.x & 63;
  const int wave = threadIdx.x >> 6;
  const int wm = wave >> 1, wn = wave & 1;
  const int l15 = lane & 15, lg = lane >> 4;
  #pragma unroll
  for (int i = 0; i < 4; ++i) {
    #pragma unroll
    for (int j = 0; j < 4; ++j) {
      const int ncol = n0 + wn * 64 + j * 16 + l15;
      const float bb = bp[ncol];
      #pragma unroll
      for (int r = 0; r < 4; ++r) {
        const int mrow = m0 + wm * 64 + i * 16 + lg * 4 + r;
        if (mrow < MTOT) out[(size_t)mrow * DMODEL + ncol] = acc[i][j][r] + bb;
      }
    }
  }
}

// ---------------- flash attention: 8-wave blocks, LDS-staged K/V, swizzled reads ----
// Block = 512 threads = 8 waves, covers (bh, 256 q-rows); wave wid owns q-tile
// qblk*8+wid (32 rows). K and V^T tiles (64 keys) are LDS-staged coalesced via
// global_load_lds (linear dest) with INVERSE-swizzled source granule g = p^(r&7)
// (rule #21); reads apply the same XOR -> 32-way bank conflict reduced to 4-way.
// Double-buffered, one __syncthreads per tile (drains vmcnt).
// Lane owns q = q0 + (lane&31). Scores: D[key][q] = mfma(K, Q).
// PV: out^T[d][q] = mfma(V^T, P). C/D: col = lane&31, row = crow(r,hi) = (r&3)+8*(r>>2)+4*hi.

// build the two B-fragments (32 keys) for one score vector
__device__ __forceinline__ void build_pa(const f32x16& s, int hi, bf16x8 pa[2]) {
  #pragma unroll
  for (int sl2 = 0; sl2 < 2; ++sl2) {
    const int off = sl2 * 8;
    unsigned w0 = pkbf(s[off + 0], s[off + 1]);
    unsigned w1 = pkbf(s[off + 2], s[off + 3]);
    unsigned w2 = pkbf(s[off + 4], s[off + 5]);
    unsigned w3 = pkbf(s[off + 6], s[off + 7]);
    unsigned p0 = shfl32u(w0), p1 = shfl32u(w1);
    unsigned p2 = shfl32u(w2), p3 = shfl32u(w3);
    unsigned pw[4];
    pw[0] = hi ? p2 : w0;
    pw[1] = hi ? p3 : w1;
    pw[2] = hi ? w2 : p0;
    pw[3] = hi ? w3 : p1;
    __builtin_memcpy(&pa[sl2], pw, 16);
  }
}

// stage one 64x64 K tile + one 64x64 V^T tile into LDS (coalesced, src-swizzled).
// thread tid -> linear LDS granule tid (byte tid*16); holds global granule p^(r&7).
__device__ __forceinline__ void stage_kv(const __bf16* __restrict__ Kp,
                                         const __bf16* __restrict__ Vp,
                                         __bf16* kls, __bf16* vls,
                                         int k0, int tid) {
  const int r = tid >> 3, p = tid & 7;
  const int g = p ^ (r & 7);
  // K rows k0+r may overrun SEQ into the zeroed V^T region (valid memory; masked)
  async16(Kp + (size_t)(k0 + r) * HDIM + g * 8, kls + tid * 8);
  // V^T row d=r, cols k0+g*8; tail-tile granules past SPAD are never consumed -> clamp
  int col = k0 + g * 8;
  if (col >= SPAD) col = 0;
  async16(Vp + (size_t)r * SPAD + col, vls + tid * 8);
}

// one 32-key step: scores + online softmax + PV, all fragments from LDS
template<bool MASK>
__device__ __forceinline__ void attn_step(const __bf16* __restrict__ kls,
                                          const __bf16* __restrict__ vls,
                                          int half, const bf16x8 (&qf)[4],
                                          int l31, int hi,
                                          float& mrun, float& lrun,
                                          f32x16& o0, f32x16& o1) {
  const int kr = half * 32 + l31;
  const int krx = kr & 7;

  f32x16 s;
  #pragma unroll
  for (int r = 0; r < 16; ++r) s[r] = 0.f;
  #pragma unroll
  for (int sl = 0; sl < 4; ++sl) {
    bf16x8 kf = *(const bf16x8*)&kls[(kr * 8 + ((2 * sl + hi) ^ krx)) * 8];
    s = __builtin_amdgcn_mfma_f32_32x32x16_bf16(kf, qf[sl], s, 0, 0, 0);
  }
  if (MASK) {  // only key k0 (crow==0: r==0 && hi==0) valid in the tail step
    #pragma unroll
    for (int r = 1; r < 16; ++r) s[r] = -1e30f;
    if (hi) s[0] = -1e30f;
  }

  const float mloc = pairmax(tree_max16(s));
  if (!__all(mloc - mrun <= 8.f)) {   // defer-max (T13)
    const float mnew = fmaxf(mrun, mloc);
    const float corr = EXP2F(mrun - mnew);
    lrun *= corr;
    #pragma unroll
    for (int r = 0; r < 16; ++r) { o0[r] *= corr; o1[r] *= corr; }
    mrun = mnew;
  }

  #pragma unroll
  for (int r = 0; r < 16; ++r) s[r] = EXP2F(s[r] - mrun);
  lrun += pairsum(tree_sum16(s));

  bf16x8 pa[2];
  build_pa(s, hi, pa);

  #pragma unroll
  for (int ot = 0; ot < 2; ++ot) {
    const int vr = ot * 32 + l31;
    const int vrx = vr & 7;
    f32x16& o = ot ? o1 : o0;
    #pragma unroll
    for (int j = 0; j < 2; ++j) {
      bf16x8 vf = *(const bf16x8*)&vls[(vr * 8 + ((half * 4 + 2 * j + hi) ^ vrx)) * 8];
      o = __builtin_amdgcn_mfma_f32_32x32x16_bf16(vf, pa[j], o, 0, 0, 0);
    }
  }
}

__global__ void __launch_bounds__(512, 4)
attn_kernel(const __bf16* __restrict__ qb, const __bf16* __restrict__ kb,
            const __bf16* __restrict__ vtb, __bf16* __restrict__ ao) {
  __shared__ __bf16 kls[2][64 * 64];   // 8 KB each
  __shared__ __bf16 vls[2][64 * 64];   // 8 KB each  (total 32 KB)

  const int tid  = threadIdx.x;
  const int wid  = tid >> 6;
  const int lane = tid & 63;
  const int l31 = lane & 31, hi = (lane >> 5) & 1;

  // XCD-aware swizzle (T1), bijective: 480 = 8 * 60, 60 = 12 bh * 5 qblk per XCD.
  // Per-XCD K+V working set = 12 bh * ~270 KB = 3.2 MB <= 4 MB L2.
  const int bid = blockIdx.x;
  const int xcd = bid & 7;
  const int ixd = bid >> 3;                  // 0..59
  const int bh  = xcd * (BHTOT / 8) + ixd / 5;
  const int qblk = ixd % 5;
  const int qt  = qblk * 8 + wid;            // 0..39; >=33 idle (staging+barriers only)
  const bool active = qt < QT32;

  const __bf16* Qp = qb + (size_t)bh * SEQ * HDIM;
  const __bf16* Kp = kb + (size_t)bh * SEQ * HDIM;
  const __bf16* Vp = vtb + (size_t)bh * HDIM * SPAD;

  const int qidx = qt * 32 + l31;
  const int qc = (qidx < SEQ ? qidx : SEQ - 1);
  bf16x8 qf[4];
  if (active) {
    #pragma unroll
    for (int sl = 0; sl < 4; ++sl)
      qf[sl] = *(const bf16x8*)&Qp[(size_t)qc * HDIM + sl * 16 + hi * 8];
  }

  f32x16 o0, o1;
  #pragma unroll
  for (int r = 0; r < 16; ++r) { o0[r] = 0.f; o1[r] = 0.f; }
  float mrun = -1e30f, lrun = 0.f;

  stage_kv(Kp, Vp, kls[0], vls[0], 0, tid);
  __syncthreads();                       // drains vmcnt(0): tile 0 ready

  for (int t = 0; t < NTILE; ++t) {
    const int cur = t & 1;
    if (t + 1 < NTILE)
      stage_kv(Kp, Vp, kls[cur ^ 1], vls[cur ^ 1], (t + 1) * 64, tid);
    if (active) {
      if (t < NTILE - 1) {
        attn_step<false>(kls[cur], vls[cur], 0, qf, l31, hi, mrun, lrun, o0, o1);
        attn_step<false>(kls[cur], vls[cur], 1, qf, l31, hi, mrun, lrun, o0, o1);
      } else {
        // tail tile: keys 1024..1087; only 1024 valid (step 0, masked); step 1 all-masked -> skip
        attn_step<true>(kls[cur], vls[cur], 0, qf, l31, hi, mrun, lrun, o0, o1);
      }
    }
    __syncthreads();                     // drains staging vmcnt + WAR protection
  }

  // epilogue: out[q][d], d = t*32 + 8g + 4*hi + u  (crow inverse)
  if (active && qidx < SEQ) {
    const int b = bh / NHEAD, h = bh % NHEAD;
    const float inv = 1.f / lrun;
    __bf16* base = ao + ((size_t)b * SEQ + qidx) * DMODEL + h * HDIM + hi * 4;
    #pragma unroll
    for (int t = 0; t < 2; ++t) {
      const f32x16& o = t ? o1 : o0;
      #pragma unroll
      for (int g = 0; g < 4; ++g) {
        bf16x4 w;
        #pragma unroll
        for (int u = 0; u < 4; ++u) w[u] = (__bf16)(o[g * 4 + u] * inv);
        *(bf16x4*)(base + t * 32 + g * 8) = w;
      }
    }
  }
}

// ---------------- launcher ----------------
extern "C" void kernel_launch(void* const* d_in, const int* in_sizes, int n_in,
                              void* d_out, int out_size, void* d_ws, size_t ws_size,
                              hipStream_t stream) {
  const float* x  = (const float*)d_in[0];
  const float* Wk = (const float*)d_in[1];
  const float* bk = (const float*)d_in[2];
  const float* Wq = (const float*)d_in[3];
  const float* bq = (const float*)d_in[4];
  const float* Wv = (const float*)d_in[5];
  const float* bv = (const float*)d_in[6];
  const float* Wp = (const float*)d_in[7];
  const float* bp = (const float*)d_in[8];
  float* out = (float*)d_out;

  if (ws_size < WS_NEEDED) return;

  char* ws = (char*)d_ws;
  __bf16* xb  = (__bf16*)(ws + XB_OFF);
  __bf16* wqb = (__bf16*)(ws + WQB_OFF);
  __bf16* wkb = (__bf16*)(ws + WKB_OFF);
  __bf16* wvb = (__bf16*)(ws + WVB_OFF);
  __bf16* wpb = (__bf16*)(ws + WPB_OFF);
  __bf16* qb  = (__bf16*)(ws + QB_OFF);
  __bf16* kb  = (__bf16*)(ws + KB_OFF);
  __bf16* vtb = (__bf16*)(ws + VT_OFF);
  __bf16* ab  = (__bf16*)(ws + AO_OFF);  // aliases xb

  // zero V^T (incl. padded tail columns 1025..1055 -> exact 0 * 0 in PV, no NaN;
  // also the region K-tail staging overruns into)
  hipMemsetAsync(vtb, 0, VT_SZ, stream);

  {
    const int n_src = MTOT * DMODEL, n_dst = MPAD * DMODEL;
    convert_f32_bf16<<<dim3((n_dst / 4 + 255) / 256), dim3(256), 0, stream>>>(x, xb, n_src, n_dst);
    const int nw = DMODEL * DMODEL;
    convert_w4<<<dim3((nw / 4 + 255) / 256, 4), dim3(256), 0, stream>>>(Wq, Wk, Wv, Wp, wqb);
  }

  gemm_qkv_kernel<<<dim3(MPAD / 128, DMODEL / 128, 3), dim3(256), 0, stream>>>(
      xb, wqb, wkb, wvb, bq, bk, bv, qb, kb, vtb);

  attn_kernel<<<dim3(8 * (BHTOT / 8) * 5), dim3(512), 0, stream>>>(qb, kb, vtb, ab);

  gemm_proj_kernel<<<dim3(MPAD / 128, DMODEL / 128), dim3(256), 0, stream>>>(
      ab, wpb, bp, out);
}

// Round 9
// 189.818 us; speedup vs baseline: 1.2194x; 1.0229x over previous
//
#include <hip/hip_runtime.h>
#include <stdint.h>

// ---------------- problem constants ----------------
#define BATCH  8
#define SEQ    1025
#define DMODEL 768
#define NHEAD  12
#define HDIM   64
#define MTOT   (BATCH * SEQ)   // 8200 tokens
#define MPAD   8320            // 65 * 128
#define SPAD   1056            // 33 * 32 (padded key length, zero-filled)
#define BHTOT  (BATCH * NHEAD) // 96
#define QT32   33              // ceil(1025/32) q-tiles of 32
#define NTILE  17              // ceil(1025/64) KV tiles of 64
#define QKSCALE 0.18033688011112042f   // 0.125 * log2(e) -> exp2-domain softmax

typedef __bf16 bf16x8 __attribute__((ext_vector_type(8)));
typedef __bf16 bf16x4 __attribute__((ext_vector_type(4)));
typedef float  f32x4  __attribute__((ext_vector_type(4)));
typedef float  f32x16 __attribute__((ext_vector_type(16)));

#if __has_builtin(__builtin_amdgcn_exp2f)
#define EXP2F __builtin_amdgcn_exp2f
#else
#define EXP2F exp2f
#endif

// ---------------- workspace layout (bytes) ----------------
constexpr size_t XB_OFF  = 0;
constexpr size_t XB_SZ   = (size_t)MPAD * DMODEL * 2;
constexpr size_t W_SZ    = (size_t)DMODEL * DMODEL * 2;
constexpr size_t WQB_OFF = XB_OFF + XB_SZ;                  // Wq,Wk,Wv,Wp contiguous (stacked)
constexpr size_t WKB_OFF = WQB_OFF + W_SZ;
constexpr size_t WVB_OFF = WKB_OFF + W_SZ;
constexpr size_t WPB_OFF = WVB_OFF + W_SZ;
constexpr size_t QB_OFF  = WPB_OFF + W_SZ;
constexpr size_t QB_SZ   = (size_t)BHTOT * SEQ * HDIM * 2;
constexpr size_t KB_OFF  = QB_OFF + QB_SZ;
constexpr size_t VT_OFF  = KB_OFF + QB_SZ;                  // K-tail overrun lands here (zeros)
constexpr size_t VT_SZ   = (size_t)BHTOT * HDIM * SPAD * 2;
constexpr size_t AO_OFF  = XB_OFF;                          // alias: xb consumed before attn writes
constexpr size_t WS_NEEDED = VT_OFF + VT_SZ;

// ---------------- helpers ----------------
__device__ __forceinline__ void async16(const void* g, void* l) {
  __builtin_amdgcn_global_load_lds((__attribute__((address_space(1))) void*)g,
                                   (__attribute__((address_space(3))) void*)l,
                                   16, 0, 0);
}

// pack two f32 -> bf16x2 dword (lo = first arg); compiler emits cvt_pk.
__device__ __forceinline__ unsigned pkbf(float lo, float hi) {
  __bf16 l = (__bf16)lo, h = (__bf16)hi;
  unsigned short lb = __builtin_bit_cast(unsigned short, l);
  unsigned short hb = __builtin_bit_cast(unsigned short, h);
  return ((unsigned)hb << 16) | (unsigned)lb;
}
__device__ __forceinline__ unsigned shfl32u(unsigned x) {   // partner half's value
  return (unsigned)__shfl_xor((int)x, 32, 64);
}
__device__ __forceinline__ float pairmax(float x) {  // max(own, lane^32)
  return fmaxf(x, __shfl_xor(x, 32, 64));
}
__device__ __forceinline__ float pairsum(float x) {  // own + lane^32
  return x + __shfl_xor(x, 32, 64);
}

// balanced trees (fp not reassociable by compiler without fast-math)
__device__ __forceinline__ float tree_max16(const f32x16& s) {
  float a0 = fmaxf(s[0], s[1]),   a1 = fmaxf(s[2], s[3]);
  float a2 = fmaxf(s[4], s[5]),   a3 = fmaxf(s[6], s[7]);
  float a4 = fmaxf(s[8], s[9]),   a5 = fmaxf(s[10], s[11]);
  float a6 = fmaxf(s[12], s[13]), a7 = fmaxf(s[14], s[15]);
  float b0 = fmaxf(a0, a1), b1 = fmaxf(a2, a3);
  float b2 = fmaxf(a4, a5), b3 = fmaxf(a6, a7);
  return fmaxf(fmaxf(b0, b1), fmaxf(b2, b3));
}
__device__ __forceinline__ float tree_sum16(const f32x16& s) {
  float a0 = s[0] + s[1],   a1 = s[2] + s[3];
  float a2 = s[4] + s[5],   a3 = s[6] + s[7];
  float a4 = s[8] + s[9],   a5 = s[10] + s[11];
  float a6 = s[12] + s[13], a7 = s[14] + s[15];
  float b0 = a0 + a1, b1 = a2 + a3, b2 = a4 + a5, b3 = a6 + a7;
  return (b0 + b1) + (b2 + b3);
}

// ---------------- fp32 -> bf16 conversion (zero-fills dst beyond n_src) ----------------
__global__ void __launch_bounds__(256)
convert_f32_bf16(const float* __restrict__ src, __bf16* __restrict__ dst,
                 int n_src, int n_dst) {
  int idx = (blockIdx.x * 256 + threadIdx.x) * 4;
  if (idx >= n_dst) return;
  bf16x4 o;
  if (idx + 3 < n_src) {
    float4 v = *(const float4*)&src[idx];
    o[0] = (__bf16)v.x; o[1] = (__bf16)v.y; o[2] = (__bf16)v.z; o[3] = (__bf16)v.w;
  } else {
    #pragma unroll
    for (int t = 0; t < 4; ++t) {
      int k = idx + t;
      o[t] = (k < n_src) ? (__bf16)src[k] : (__bf16)0.f;
    }
  }
  *(bf16x4*)&dst[idx] = o;
}

// 4 weight matrices in one launch; dst regions are contiguous (WQB..WPB).
__global__ void __launch_bounds__(256)
convert_w4(const float* __restrict__ w0, const float* __restrict__ w1,
           const float* __restrict__ w2, const float* __restrict__ w3,
           __bf16* __restrict__ dst) {
  const int which = blockIdx.y;
  const float* src = (which == 0) ? w0 : (which == 1) ? w1 : (which == 2) ? w2 : w3;
  __bf16* d = dst + (size_t)which * DMODEL * DMODEL;
  int idx = (blockIdx.x * 256 + threadIdx.x) * 4;
  if (idx >= DMODEL * DMODEL) return;
  float4 v = *(const float4*)&src[idx];
  bf16x4 o;
  o[0] = (__bf16)v.x; o[1] = (__bf16)v.y; o[2] = (__bf16)v.z; o[3] = (__bf16)v.w;
  *(bf16x4*)&d[idx] = o;
}

// ---------------- shared 128x128 GEMM core: C = A @ W^T ----------------
__device__ __forceinline__ void gemm_core(const __bf16* __restrict__ A,
                                          const __bf16* __restrict__ W,
                                          __bf16* As, __bf16* Bs,
                                          int m0, int n0, f32x4 acc[4][4]) {
  const int tid  = threadIdx.x;
  const int lane = tid & 63;
  const int wave = tid >> 6;
  const int wm = wave >> 1, wn = wave & 1;
  const int l15 = lane & 15, lg = lane >> 4;

  for (int kt = 0; kt < DMODEL; kt += 64) {
    __syncthreads();
    #pragma unroll
    for (int i = 0; i < 4; ++i) {
      int e = (i * 256 + tid) * 8;
      int r = e >> 6, c = e & 63;
      async16(A + (size_t)(m0 + r) * DMODEL + kt + c, As + e);
      async16(W + (size_t)(n0 + r) * DMODEL + kt + c, Bs + e);
    }
    __syncthreads();
    #pragma unroll
    for (int kk = 0; kk < 2; ++kk) {
      bf16x8 af[4], bfr[4];
      #pragma unroll
      for (int i = 0; i < 4; ++i)
        af[i] = *(const bf16x8*)&As[(wm * 64 + i * 16 + l15) * 64 + kk * 32 + lg * 8];
      #pragma unroll
      for (int j = 0; j < 4; ++j)
        bfr[j] = *(const bf16x8*)&Bs[(wn * 64 + j * 16 + l15) * 64 + kk * 32 + lg * 8];
      #pragma unroll
      for (int i = 0; i < 4; ++i)
        #pragma unroll
        for (int j = 0; j < 4; ++j)
          acc[i][j] = __builtin_amdgcn_mfma_f32_16x16x32_bf16(af[i], bfr[j], acc[i][j], 0, 0, 0);
    }
  }
}

// ---------------- fused QKV projection: one GEMM vs stacked W [2304][768] ----------------
// Grid: 1170 blocks (65 m-blocks x 18 n-blocks), XCD-partitioned along m (bijective,
// NB=1170: q=146,r=2): each XCD owns ~8 consecutive m-blocks, n fastest -> A-tile
// stays L2-resident across all 18 n-sweeps; W (3.5 MB) cycles L2-resident per XCD.
__global__ void __launch_bounds__(256)
gemm_qkv_kernel(const __bf16* __restrict__ xb, const __bf16* __restrict__ wsb,
                const float* __restrict__ bq, const float* __restrict__ bk,
                const float* __restrict__ bv,
                __bf16* __restrict__ qb, __bf16* __restrict__ kb,
                __bf16* __restrict__ vtb) {
  __shared__ __bf16 As[128 * 64];
  __shared__ __bf16 Bs[128 * 64];
  const int wg  = blockIdx.x;
  const int xcd = wg & 7, idx = wg >> 3;
  const int v   = xcd * 146 + (xcd < 2 ? xcd : 2) + idx;   // bijective virtual index
  const int m0  = (v / 18) * 128;
  const int n0  = (v % 18) * 128;                          // 0..2176 in stacked-N

  f32x4 acc[4][4];
  #pragma unroll
  for (int i = 0; i < 4; ++i)
    #pragma unroll
    for (int j = 0; j < 4; ++j) acc[i][j] = (f32x4){0.f, 0.f, 0.f, 0.f};

  gemm_core(xb, wsb, As, Bs, m0, n0, acc);

  const int lane = threadIdx.x & 63;
  const int wave = threadIdx.x >> 6;
  const int wm = wave >> 1, wn = wave & 1;
  const int l15 = lane & 15, lg = lane >> 4;
  #pragma unroll
  for (int i = 0; i < 4; ++i) {
    #pragma unroll
    for (int j = 0; j < 4; ++j) {
      const int ncolg = n0 + wn * 64 + j * 16 + l15;       // 0..2303
      // 768 % 16 == 0 -> all 16 lanes of a j-iter share one mode (wave-uniform branch)
      const int mode = ncolg / 768;
      const int col  = ncolg - mode * 768;
      const float bb = (mode == 0 ? bq : (mode == 1 ? bk : bv))[col];
      const int h = col >> 6, hd = col & 63;
      #pragma unroll
      for (int r = 0; r < 4; ++r) {
        const int mrow = m0 + wm * 64 + i * 16 + lg * 4 + r;
        if (mrow < MTOT) {
          float val = acc[i][j][r] + bb;
          const int b = mrow / SEQ;
          const int s = mrow - b * SEQ;
          const int bh = b * NHEAD + h;
          if (mode == 2)
            vtb[((size_t)bh * HDIM + hd) * SPAD + s] = (__bf16)val;
          else if (mode == 0)
            qb[((size_t)bh * SEQ + s) * HDIM + hd] = (__bf16)(val * QKSCALE);
          else
            kb[((size_t)bh * SEQ + s) * HDIM + hd] = (__bf16)val;
        }
      }
    }
  }
}

// ---------------- output projection (m-partitioned XCD swizzle, NB=390: q=48,r=6) ----
__global__ void __launch_bounds__(256)
gemm_proj_kernel(const __bf16* __restrict__ ab, const __bf16* __restrict__ wpb,
                 const float* __restrict__ bp, float* __restrict__ out) {
  __shared__ __bf16 As[128 * 64];
  __shared__ __bf16 Bs[128 * 64];
  const int wg  = blockIdx.x;
  const int xcd = wg & 7, idx = wg >> 3;
  const int v   = xcd * 48 + (xcd < 6 ? xcd : 6) + idx;
  const int m0  = (v / 6) * 128;
  const int n0  = (v % 6) * 128;

  f32x4 acc[4][4];
  #pragma unroll
  for (int i = 0; i < 4; ++i)
    #pragma unroll
    for (int j = 0; j < 4; ++j) acc[i][j] = (f32x4){0.f, 0.f, 0.f, 0.f};

  gemm_core(ab, wpb, As, Bs, m0, n0, acc);

  const int lane = threadIdx.x & 63;
  const int wave = threadIdx.x >> 6;
  const int wm = wave >> 1, wn = wave & 1;
  const int l15 = lane & 15, lg = lane >> 4;
  #pragma unroll
  for (int i = 0; i < 4; ++i) {
    #pragma unroll
    for (int j = 0; j < 4; ++j) {
      const int ncol = n0 + wn * 64 + j * 16 + l15;
      const float bb = bp[ncol];
      #pragma unroll
      for (int r = 0; r < 4; ++r) {
        const int mrow = m0 + wm * 64 + i * 16 + lg * 4 + r;
        if (mrow < MTOT) out[(size_t)mrow * DMODEL + ncol] = acc[i][j][r] + bb;
      }
    }
  }
}

// ---------------- flash attention: 8-wave blocks, LDS-staged K/V, swizzled reads ----
// (unchanged from Round 8 — see that round's notes)
__device__ __forceinline__ void build_pa(const f32x16& s, int hi, bf16x8 pa[2]) {
  #pragma unroll
  for (int sl2 = 0; sl2 < 2; ++sl2) {
    const int off = sl2 * 8;
    unsigned w0 = pkbf(s[off + 0], s[off + 1]);
    unsigned w1 = pkbf(s[off + 2], s[off + 3]);
    unsigned w2 = pkbf(s[off + 4], s[off + 5]);
    unsigned w3 = pkbf(s[off + 6], s[off + 7]);
    unsigned p0 = shfl32u(w0), p1 = shfl32u(w1);
    unsigned p2 = shfl32u(w2), p3 = shfl32u(w3);
    unsigned pw[4];
    pw[0] = hi ? p2 : w0;
    pw[1] = hi ? p3 : w1;
    pw[2] = hi ? w2 : p0;
    pw[3] = hi ? w3 : p1;
    __builtin_memcpy(&pa[sl2], pw, 16);
  }
}

__device__ __forceinline__ void stage_kv(const __bf16* __restrict__ Kp,
                                         const __bf16* __restrict__ Vp,
                                         __bf16* kls, __bf16* vls,
                                         int k0, int tid) {
  const int r = tid >> 3, p = tid & 7;
  const int g = p ^ (r & 7);
  async16(Kp + (size_t)(k0 + r) * HDIM + g * 8, kls + tid * 8);
  int col = k0 + g * 8;
  if (col >= SPAD) col = 0;
  async16(Vp + (size_t)r * SPAD + col, vls + tid * 8);
}

template<bool MASK>
__device__ __forceinline__ void attn_step(const __bf16* __restrict__ kls,
                                          const __bf16* __restrict__ vls,
                                          int half, const bf16x8 (&qf)[4],
                                          int l31, int hi,
                                          float& mrun, float& lrun,
                                          f32x16& o0, f32x16& o1) {
  const int kr = half * 32 + l31;
  const int krx = kr & 7;

  f32x16 s;
  #pragma unroll
  for (int r = 0; r < 16; ++r) s[r] = 0.f;
  #pragma unroll
  for (int sl = 0; sl < 4; ++sl) {
    bf16x8 kf = *(const bf16x8*)&kls[(kr * 8 + ((2 * sl + hi) ^ krx)) * 8];
    s = __builtin_amdgcn_mfma_f32_32x32x16_bf16(kf, qf[sl], s, 0, 0, 0);
  }
  if (MASK) {
    #pragma unroll
    for (int r = 1; r < 16; ++r) s[r] = -1e30f;
    if (hi) s[0] = -1e30f;
  }

  const float mloc = pairmax(tree_max16(s));
  if (!__all(mloc - mrun <= 8.f)) {   // defer-max (T13)
    const float mnew = fmaxf(mrun, mloc);
    const float corr = EXP2F(mrun - mnew);
    lrun *= corr;
    #pragma unroll
    for (int r = 0; r < 16; ++r) { o0[r] *= corr; o1[r] *= corr; }
    mrun = mnew;
  }

  #pragma unroll
  for (int r = 0; r < 16; ++r) s[r] = EXP2F(s[r] - mrun);
  lrun += pairsum(tree_sum16(s));

  bf16x8 pa[2];
  build_pa(s, hi, pa);

  #pragma unroll
  for (int ot = 0; ot < 2; ++ot) {
    const int vr = ot * 32 + l31;
    const int vrx = vr & 7;
    f32x16& o = ot ? o1 : o0;
    #pragma unroll
    for (int j = 0; j < 2; ++j) {
      bf16x8 vf = *(const bf16x8*)&vls[(vr * 8 + ((half * 4 + 2 * j + hi) ^ vrx)) * 8];
      o = __builtin_amdgcn_mfma_f32_32x32x16_bf16(vf, pa[j], o, 0, 0, 0);
    }
  }
}

__global__ void __launch_bounds__(512, 4)
attn_kernel(const __bf16* __restrict__ qb, const __bf16* __restrict__ kb,
            const __bf16* __restrict__ vtb, __bf16* __restrict__ ao) {
  __shared__ __bf16 kls[2][64 * 64];
  __shared__ __bf16 vls[2][64 * 64];

  const int tid  = threadIdx.x;
  const int wid  = tid >> 6;
  const int lane = tid & 63;
  const int l31 = lane & 31, hi = (lane >> 5) & 1;

  const int bid = blockIdx.x;
  const int xcd = bid & 7;
  const int ixd = bid >> 3;
  const int bh  = xcd * (BHTOT / 8) + ixd / 5;
  const int qblk = ixd % 5;
  const int qt  = qblk * 8 + wid;
  const bool active = qt < QT32;

  const __bf16* Qp = qb + (size_t)bh * SEQ * HDIM;
  const __bf16* Kp = kb + (size_t)bh * SEQ * HDIM;
  const __bf16* Vp = vtb + (size_t)bh * HDIM * SPAD;

  const int qidx = qt * 32 + l31;
  const int qc = (qidx < SEQ ? qidx : SEQ - 1);
  bf16x8 qf[4];
  if (active) {
    #pragma unroll
    for (int sl = 0; sl < 4; ++sl)
      qf[sl] = *(const bf16x8*)&Qp[(size_t)qc * HDIM + sl * 16 + hi * 8];
  }

  f32x16 o0, o1;
  #pragma unroll
  for (int r = 0; r < 16; ++r) { o0[r] = 0.f; o1[r] = 0.f; }
  float mrun = -1e30f, lrun = 0.f;

  stage_kv(Kp, Vp, kls[0], vls[0], 0, tid);
  __syncthreads();

  for (int t = 0; t < NTILE; ++t) {
    const int cur = t & 1;
    if (t + 1 < NTILE)
      stage_kv(Kp, Vp, kls[cur ^ 1], vls[cur ^ 1], (t + 1) * 64, tid);
    if (active) {
      if (t < NTILE - 1) {
        attn_step<false>(kls[cur], vls[cur], 0, qf, l31, hi, mrun, lrun, o0, o1);
        attn_step<false>(kls[cur], vls[cur], 1, qf, l31, hi, mrun, lrun, o0, o1);
      } else {
        attn_step<true>(kls[cur], vls[cur], 0, qf, l31, hi, mrun, lrun, o0, o1);
      }
    }
    __syncthreads();
  }

  if (active && qidx < SEQ) {
    const int b = bh / NHEAD, h = bh % NHEAD;
    const float inv = 1.f / lrun;
    __bf16* base = ao + ((size_t)b * SEQ + qidx) * DMODEL + h * HDIM + hi * 4;
    #pragma unroll
    for (int t = 0; t < 2; ++t) {
      const f32x16& o = t ? o1 : o0;
      #pragma unroll
      for (int g = 0; g < 4; ++g) {
        bf16x4 w;
        #pragma unroll
        for (int u = 0; u < 4; ++u) w[u] = (__bf16)(o[g * 4 + u] * inv);
        *(bf16x4*)(base + t * 32 + g * 8) = w;
      }
    }
  }
}

// ---------------- launcher ----------------
extern "C" void kernel_launch(void* const* d_in, const int* in_sizes, int n_in,
                              void* d_out, int out_size, void* d_ws, size_t ws_size,
                              hipStream_t stream) {
  const float* x  = (const float*)d_in[0];
  const float* Wk = (const float*)d_in[1];
  const float* bk = (const float*)d_in[2];
  const float* Wq = (const float*)d_in[3];
  const float* bq = (const float*)d_in[4];
  const float* Wv = (const float*)d_in[5];
  const float* bv = (const float*)d_in[6];
  const float* Wp = (const float*)d_in[7];
  const float* bp = (const float*)d_in[8];
  float* out = (float*)d_out;

  if (ws_size < WS_NEEDED) return;

  char* ws = (char*)d_ws;
  __bf16* xb  = (__bf16*)(ws + XB_OFF);
  __bf16* wqb = (__bf16*)(ws + WQB_OFF);   // stacked Wq|Wk|Wv|Wp
  __bf16* wpb = (__bf16*)(ws + WPB_OFF);
  __bf16* qb  = (__bf16*)(ws + QB_OFF);
  __bf16* kb  = (__bf16*)(ws + KB_OFF);
  __bf16* vtb = (__bf16*)(ws + VT_OFF);
  __bf16* ab  = (__bf16*)(ws + AO_OFF);    // aliases xb

  // zero V^T (incl. padded tail columns 1025..1055 -> exact 0 * 0 in PV, no NaN;
  // also the region K-tail staging overruns into)
  hipMemsetAsync(vtb, 0, VT_SZ, stream);

  {
    const int n_src = MTOT * DMODEL, n_dst = MPAD * DMODEL;
    convert_f32_bf16<<<dim3((n_dst / 4 + 255) / 256), dim3(256), 0, stream>>>(x, xb, n_src, n_dst);
    const int nw = DMODEL * DMODEL;
    convert_w4<<<dim3((nw / 4 + 255) / 256, 4), dim3(256), 0, stream>>>(Wq, Wk, Wv, Wp, wqb);
  }

  // fused QKV GEMM: 65 m-blocks x 18 stacked-n-blocks = 1170
  gemm_qkv_kernel<<<dim3(1170), dim3(256), 0, stream>>>(
      xb, wqb, bq, bk, bv, qb, kb, vtb);

  attn_kernel<<<dim3(8 * (BHTOT / 8) * 5), dim3(512), 0, stream>>>(qb, kb, vtb, ab);

  // projection GEMM: 65 x 6 = 390
  gemm_proj_kernel<<<dim3(390), dim3(256), 0, stream>>>(ab, wpb, bp, out);
}

// Round 10
// 176.296 us; speedup vs baseline: 1.3130x; 1.0767x over previous
//
#include <hip/hip_runtime.h>
#include <stdint.h>

// ---------------- problem constants ----------------
#define BATCH  8
#define SEQ    1025
#define DMODEL 768
#define NHEAD  12
#define HDIM   64
#define MTOT   (BATCH * SEQ)   // 8200 tokens
#define MPAD   8320            // 65 * 128
#define SPAD   1056            // 33 * 32 (padded key length, zero-filled)
#define BHTOT  (BATCH * NHEAD) // 96
#define QT32   33              // ceil(1025/32) q-tiles of 32
#define NTILE  17              // ceil(1025/64) KV tiles of 64
#define QKSCALE 0.18033688011112042f   // 0.125 * log2(e) -> exp2-domain softmax

typedef __bf16 bf16x8 __attribute__((ext_vector_type(8)));
typedef __bf16 bf16x4 __attribute__((ext_vector_type(4)));
typedef float  f32x4  __attribute__((ext_vector_type(4)));
typedef float  f32x16 __attribute__((ext_vector_type(16)));

#if __has_builtin(__builtin_amdgcn_exp2f)
#define EXP2F __builtin_amdgcn_exp2f
#else
#define EXP2F exp2f
#endif

// ---------------- workspace layout (bytes) ----------------
constexpr size_t XB_OFF  = 0;
constexpr size_t XB_SZ   = (size_t)MPAD * DMODEL * 2;
constexpr size_t W_SZ    = (size_t)DMODEL * DMODEL * 2;
constexpr size_t WQB_OFF = XB_OFF + XB_SZ;                  // Wq,Wk,Wv,Wp contiguous (stacked)
constexpr size_t WKB_OFF = WQB_OFF + W_SZ;
constexpr size_t WVB_OFF = WKB_OFF + W_SZ;
constexpr size_t WPB_OFF = WVB_OFF + W_SZ;
constexpr size_t QB_OFF  = WPB_OFF + W_SZ;
constexpr size_t QB_SZ   = (size_t)BHTOT * SEQ * HDIM * 2;
constexpr size_t KB_OFF  = QB_OFF + QB_SZ;
constexpr size_t VT_OFF  = KB_OFF + QB_SZ;                  // K-tail overrun lands here (zeros)
constexpr size_t VT_SZ   = (size_t)BHTOT * HDIM * SPAD * 2;
constexpr size_t AO_OFF  = XB_OFF;                          // alias: xb consumed before attn writes
constexpr size_t WS_NEEDED = VT_OFF + VT_SZ;

// ---------------- helpers ----------------
__device__ __forceinline__ void async16(const void* g, void* l) {
  __builtin_amdgcn_global_load_lds((__attribute__((address_space(1))) void*)g,
                                   (__attribute__((address_space(3))) void*)l,
                                   16, 0, 0);
}

// pack two f32 -> bf16x2 dword (lo = first arg); compiler emits cvt_pk.
__device__ __forceinline__ unsigned pkbf(float lo, float hi) {
  __bf16 l = (__bf16)lo, h = (__bf16)hi;
  unsigned short lb = __builtin_bit_cast(unsigned short, l);
  unsigned short hb = __builtin_bit_cast(unsigned short, h);
  return ((unsigned)hb << 16) | (unsigned)lb;
}
__device__ __forceinline__ unsigned shfl32u(unsigned x) {   // partner half's value
  return (unsigned)__shfl_xor((int)x, 32, 64);
}
__device__ __forceinline__ float pairmax(float x) {  // max(own, lane^32)
  return fmaxf(x, __shfl_xor(x, 32, 64));
}
__device__ __forceinline__ float pairsum(float x) {  // own + lane^32
  return x + __shfl_xor(x, 32, 64);
}

// balanced trees (fp not reassociable by compiler without fast-math)
__device__ __forceinline__ float tree_max16(const f32x16& s) {
  float a0 = fmaxf(s[0], s[1]),   a1 = fmaxf(s[2], s[3]);
  float a2 = fmaxf(s[4], s[5]),   a3 = fmaxf(s[6], s[7]);
  float a4 = fmaxf(s[8], s[9]),   a5 = fmaxf(s[10], s[11]);
  float a6 = fmaxf(s[12], s[13]), a7 = fmaxf(s[14], s[15]);
  float b0 = fmaxf(a0, a1), b1 = fmaxf(a2, a3);
  float b2 = fmaxf(a4, a5), b3 = fmaxf(a6, a7);
  return fmaxf(fmaxf(b0, b1), fmaxf(b2, b3));
}
__device__ __forceinline__ float tree_sum16(const f32x16& s) {
  float a0 = s[0] + s[1],   a1 = s[2] + s[3];
  float a2 = s[4] + s[5],   a3 = s[6] + s[7];
  float a4 = s[8] + s[9],   a5 = s[10] + s[11];
  float a6 = s[12] + s[13], a7 = s[14] + s[15];
  float b0 = a0 + a1, b1 = a2 + a3, b2 = a4 + a5, b3 = a6 + a7;
  return (b0 + b1) + (b2 + b3);
}

// ---------------- fp32 -> bf16 conversion (zero-fills dst beyond n_src) ----------------
__global__ void __launch_bounds__(256)
convert_f32_bf16(const float* __restrict__ src, __bf16* __restrict__ dst,
                 int n_src, int n_dst) {
  int idx = (blockIdx.x * 256 + threadIdx.x) * 4;
  if (idx >= n_dst) return;
  bf16x4 o;
  if (idx + 3 < n_src) {
    float4 v = *(const float4*)&src[idx];
    o[0] = (__bf16)v.x; o[1] = (__bf16)v.y; o[2] = (__bf16)v.z; o[3] = (__bf16)v.w;
  } else {
    #pragma unroll
    for (int t = 0; t < 4; ++t) {
      int k = idx + t;
      o[t] = (k < n_src) ? (__bf16)src[k] : (__bf16)0.f;
    }
  }
  *(bf16x4*)&dst[idx] = o;
}

// 4 weight matrices in one launch; dst regions are contiguous (WQB..WPB).
__global__ void __launch_bounds__(256)
convert_w4(const float* __restrict__ w0, const float* __restrict__ w1,
           const float* __restrict__ w2, const float* __restrict__ w3,
           __bf16* __restrict__ dst) {
  const int which = blockIdx.y;
  const float* src = (which == 0) ? w0 : (which == 1) ? w1 : (which == 2) ? w2 : w3;
  __bf16* d = dst + (size_t)which * DMODEL * DMODEL;
  int idx = (blockIdx.x * 256 + threadIdx.x) * 4;
  if (idx >= DMODEL * DMODEL) return;
  float4 v = *(const float4*)&src[idx];
  bf16x4 o;
  o[0] = (__bf16)v.x; o[1] = (__bf16)v.y; o[2] = (__bf16)v.z; o[3] = (__bf16)v.w;
  *(bf16x4*)&d[idx] = o;
}

// ---------------- shared 128x128 GEMM core: C = A @ W^T (T2-swizzled LDS) ----------------
// LDS tile rows are 64 elem = 128 B = exactly 32 banks -> unswizzled ds_read_b128 across
// l15 lanes is a 16-way bank conflict (SQ_LDS_BANK_CONFLICT 1.1e7, ~80% of r9 dur).
// Fix per rule #21 (both-sides-or-neither with global_load_lds): LDS dest stays LINEAR,
// the global SOURCE granule is inverse-swizzled g = p ^ (r&7), and reads XOR the same
// way -> granule' = (kk*4+lg) ^ (l15&7): l15 0..7 hit 8 distinct bank-quads, 8..15
// repeat them = 2 lanes/bank = free (m136).
__device__ __forceinline__ void gemm_core(const __bf16* __restrict__ A,
                                          const __bf16* __restrict__ W,
                                          __bf16* As, __bf16* Bs,
                                          int m0, int n0, f32x4 acc[4][4]) {
  const int tid  = threadIdx.x;
  const int lane = tid & 63;
  const int wave = tid >> 6;
  const int wm = wave >> 1, wn = wave & 1;
  const int l15 = lane & 15, lg = lane >> 4;
  const int rx  = l15 & 7;               // read-side XOR key (row & 7)

  for (int kt = 0; kt < DMODEL; kt += 64) {
    __syncthreads();
    #pragma unroll
    for (int i = 0; i < 4; ++i) {
      const int gi = i * 256 + tid;      // granule index 0..1023 (16 B granules)
      const int r  = gi >> 3;            // tile row 0..127
      const int p  = gi & 7;             // LDS granule within row (linear dest)
      const int g  = p ^ (r & 7);        // inverse-swizzled SOURCE granule
      async16(A + (size_t)(m0 + r) * DMODEL + kt + g * 8, As + gi * 8);
      async16(W + (size_t)(n0 + r) * DMODEL + kt + g * 8, Bs + gi * 8);
    }
    __syncthreads();
    #pragma unroll
    for (int kk = 0; kk < 2; ++kk) {
      bf16x8 af[4], bfr[4];
      #pragma unroll
      for (int i = 0; i < 4; ++i)
        af[i] = *(const bf16x8*)&As[(wm * 64 + i * 16 + l15) * 64 + (((kk * 4 + lg) ^ rx)) * 8];
      #pragma unroll
      for (int j = 0; j < 4; ++j)
        bfr[j] = *(const bf16x8*)&Bs[(wn * 64 + j * 16 + l15) * 64 + (((kk * 4 + lg) ^ rx)) * 8];
      #pragma unroll
      for (int i = 0; i < 4; ++i)
        #pragma unroll
        for (int j = 0; j < 4; ++j)
          acc[i][j] = __builtin_amdgcn_mfma_f32_16x16x32_bf16(af[i], bfr[j], acc[i][j], 0, 0, 0);
    }
  }
}

// ---------------- fused QKV projection: one GEMM vs stacked W [2304][768] ----------------
// Grid: 1170 blocks (65 m x 18 n), XCD-partitioned along m (bijective, q=146,r=2).
__global__ void __launch_bounds__(256)
gemm_qkv_kernel(const __bf16* __restrict__ xb, const __bf16* __restrict__ wsb,
                const float* __restrict__ bq, const float* __restrict__ bk,
                const float* __restrict__ bv,
                __bf16* __restrict__ qb, __bf16* __restrict__ kb,
                __bf16* __restrict__ vtb) {
  __shared__ __bf16 As[128 * 64];
  __shared__ __bf16 Bs[128 * 64];
  const int wg  = blockIdx.x;
  const int xcd = wg & 7, idx = wg >> 3;
  const int v   = xcd * 146 + (xcd < 2 ? xcd : 2) + idx;   // bijective virtual index
  const int m0  = (v / 18) * 128;
  const int n0  = (v % 18) * 128;                          // 0..2176 in stacked-N

  f32x4 acc[4][4];
  #pragma unroll
  for (int i = 0; i < 4; ++i)
    #pragma unroll
    for (int j = 0; j < 4; ++j) acc[i][j] = (f32x4){0.f, 0.f, 0.f, 0.f};

  gemm_core(xb, wsb, As, Bs, m0, n0, acc);

  const int lane = threadIdx.x & 63;
  const int wave = threadIdx.x >> 6;
  const int wm = wave >> 1, wn = wave & 1;
  const int l15 = lane & 15, lg = lane >> 4;
  #pragma unroll
  for (int i = 0; i < 4; ++i) {
    #pragma unroll
    for (int j = 0; j < 4; ++j) {
      const int ncolg = n0 + wn * 64 + j * 16 + l15;       // 0..2303
      // 768 % 16 == 0 -> all 16 lanes of a j-iter share one mode (wave-uniform branch)
      const int mode = ncolg / 768;
      const int col  = ncolg - mode * 768;
      const float bb = (mode == 0 ? bq : (mode == 1 ? bk : bv))[col];
      const int h = col >> 6, hd = col & 63;
      #pragma unroll
      for (int r = 0; r < 4; ++r) {
        const int mrow = m0 + wm * 64 + i * 16 + lg * 4 + r;
        if (mrow < MTOT) {
          float val = acc[i][j][r] + bb;
          const int b = mrow / SEQ;
          const int s = mrow - b * SEQ;
          const int bh = b * NHEAD + h;
          if (mode == 2)
            vtb[((size_t)bh * HDIM + hd) * SPAD + s] = (__bf16)val;
          else if (mode == 0)
            qb[((size_t)bh * SEQ + s) * HDIM + hd] = (__bf16)(val * QKSCALE);
          else
            kb[((size_t)bh * SEQ + s) * HDIM + hd] = (__bf16)val;
        }
      }
    }
  }
}

// ---------------- output projection (m-partitioned XCD swizzle, NB=390: q=48,r=6) ----
__global__ void __launch_bounds__(256)
gemm_proj_kernel(const __bf16* __restrict__ ab, const __bf16* __restrict__ wpb,
                 const float* __restrict__ bp, float* __restrict__ out) {
  __shared__ __bf16 As[128 * 64];
  __shared__ __bf16 Bs[128 * 64];
  const int wg  = blockIdx.x;
  const int xcd = wg & 7, idx = wg >> 3;
  const int v   = xcd * 48 + (xcd < 6 ? xcd : 6) + idx;
  const int m0  = (v / 6) * 128;
  const int n0  = (v % 6) * 128;

  f32x4 acc[4][4];
  #pragma unroll
  for (int i = 0; i < 4; ++i)
    #pragma unroll
    for (int j = 0; j < 4; ++j) acc[i][j] = (f32x4){0.f, 0.f, 0.f, 0.f};

  gemm_core(ab, wpb, As, Bs, m0, n0, acc);

  const int lane = threadIdx.x & 63;
  const int wave = threadIdx.x >> 6;
  const int wm = wave >> 1, wn = wave & 1;
  const int l15 = lane & 15, lg = lane >> 4;
  #pragma unroll
  for (int i = 0; i < 4; ++i) {
    #pragma unroll
    for (int j = 0; j < 4; ++j) {
      const int ncol = n0 + wn * 64 + j * 16 + l15;
      const float bb = bp[ncol];
      #pragma unroll
      for (int r = 0; r < 4; ++r) {
        const int mrow = m0 + wm * 64 + i * 16 + lg * 4 + r;
        if (mrow < MTOT) out[(size_t)mrow * DMODEL + ncol] = acc[i][j][r] + bb;
      }
    }
  }
}

// ---------------- flash attention: 8-wave blocks, LDS-staged K/V, swizzled reads ----
// (unchanged from Round 8 — see that round's notes)
__device__ __forceinline__ void build_pa(const f32x16& s, int hi, bf16x8 pa[2]) {
  #pragma unroll
  for (int sl2 = 0; sl2 < 2; ++sl2) {
    const int off = sl2 * 8;
    unsigned w0 = pkbf(s[off + 0], s[off + 1]);
    unsigned w1 = pkbf(s[off + 2], s[off + 3]);
    unsigned w2 = pkbf(s[off + 4], s[off + 5]);
    unsigned w3 = pkbf(s[off + 6], s[off + 7]);
    unsigned p0 = shfl32u(w0), p1 = shfl32u(w1);
    unsigned p2 = shfl32u(w2), p3 = shfl32u(w3);
    unsigned pw[4];
    pw[0] = hi ? p2 : w0;
    pw[1] = hi ? p3 : w1;
    pw[2] = hi ? w2 : p0;
    pw[3] = hi ? w3 : p1;
    __builtin_memcpy(&pa[sl2], pw, 16);
  }
}

__device__ __forceinline__ void stage_kv(const __bf16* __restrict__ Kp,
                                         const __bf16* __restrict__ Vp,
                                         __bf16* kls, __bf16* vls,
                                         int k0, int tid) {
  const int r = tid >> 3, p = tid & 7;
  const int g = p ^ (r & 7);
  async16(Kp + (size_t)(k0 + r) * HDIM + g * 8, kls + tid * 8);
  int col = k0 + g * 8;
  if (col >= SPAD) col = 0;
  async16(Vp + (size_t)r * SPAD + col, vls + tid * 8);
}

template<bool MASK>
__device__ __forceinline__ void attn_step(const __bf16* __restrict__ kls,
                                          const __bf16* __restrict__ vls,
                                          int half, const bf16x8 (&qf)[4],
                                          int l31, int hi,
                                          float& mrun, float& lrun,
                                          f32x16& o0, f32x16& o1) {
  const int kr = half * 32 + l31;
  const int krx = kr & 7;

  f32x16 s;
  #pragma unroll
  for (int r = 0; r < 16; ++r) s[r] = 0.f;
  #pragma unroll
  for (int sl = 0; sl < 4; ++sl) {
    bf16x8 kf = *(const bf16x8*)&kls[(kr * 8 + ((2 * sl + hi) ^ krx)) * 8];
    s = __builtin_amdgcn_mfma_f32_32x32x16_bf16(kf, qf[sl], s, 0, 0, 0);
  }
  if (MASK) {
    #pragma unroll
    for (int r = 1; r < 16; ++r) s[r] = -1e30f;
    if (hi) s[0] = -1e30f;
  }

  const float mloc = pairmax(tree_max16(s));
  if (!__all(mloc - mrun <= 8.f)) {   // defer-max (T13)
    const float mnew = fmaxf(mrun, mloc);
    const float corr = EXP2F(mrun - mnew);
    lrun *= corr;
    #pragma unroll
    for (int r = 0; r < 16; ++r) { o0[r] *= corr; o1[r] *= corr; }
    mrun = mnew;
  }

  #pragma unroll
  for (int r = 0; r < 16; ++r) s[r] = EXP2F(s[r] - mrun);
  lrun += pairsum(tree_sum16(s));

  bf16x8 pa[2];
  build_pa(s, hi, pa);

  #pragma unroll
  for (int ot = 0; ot < 2; ++ot) {
    const int vr = ot * 32 + l31;
    const int vrx = vr & 7;
    f32x16& o = ot ? o1 : o0;
    #pragma unroll
    for (int j = 0; j < 2; ++j) {
      bf16x8 vf = *(const bf16x8*)&vls[(vr * 8 + ((half * 4 + 2 * j + hi) ^ vrx)) * 8];
      o = __builtin_amdgcn_mfma_f32_32x32x16_bf16(vf, pa[j], o, 0, 0, 0);
    }
  }
}

__global__ void __launch_bounds__(512, 4)
attn_kernel(const __bf16* __restrict__ qb, const __bf16* __restrict__ kb,
            const __bf16* __restrict__ vtb, __bf16* __restrict__ ao) {
  __shared__ __bf16 kls[2][64 * 64];
  __shared__ __bf16 vls[2][64 * 64];

  const int tid  = threadIdx.x;
  const int wid  = tid >> 6;
  const int lane = tid & 63;
  const int l31 = lane & 31, hi = (lane >> 5) & 1;

  const int bid = blockIdx.x;
  const int xcd = bid & 7;
  const int ixd = bid >> 3;
  const int bh  = xcd * (BHTOT / 8) + ixd / 5;
  const int qblk = ixd % 5;
  const int qt  = qblk * 8 + wid;
  const bool active = qt < QT32;

  const __bf16* Qp = qb + (size_t)bh * SEQ * HDIM;
  const __bf16* Kp = kb + (size_t)bh * SEQ * HDIM;
  const __bf16* Vp = vtb + (size_t)bh * HDIM * SPAD;

  const int qidx = qt * 32 + l31;
  const int qc = (qidx < SEQ ? qidx : SEQ - 1);
  bf16x8 qf[4];
  if (active) {
    #pragma unroll
    for (int sl = 0; sl < 4; ++sl)
      qf[sl] = *(const bf16x8*)&Qp[(size_t)qc * HDIM + sl * 16 + hi * 8];
  }

  f32x16 o0, o1;
  #pragma unroll
  for (int r = 0; r < 16; ++r) { o0[r] = 0.f; o1[r] = 0.f; }
  float mrun = -1e30f, lrun = 0.f;

  stage_kv(Kp, Vp, kls[0], vls[0], 0, tid);
  __syncthreads();

  for (int t = 0; t < NTILE; ++t) {
    const int cur = t & 1;
    if (t + 1 < NTILE)
      stage_kv(Kp, Vp, kls[cur ^ 1], vls[cur ^ 1], (t + 1) * 64, tid);
    if (active) {
      if (t < NTILE - 1) {
        attn_step<false>(kls[cur], vls[cur], 0, qf, l31, hi, mrun, lrun, o0, o1);
        attn_step<false>(kls[cur], vls[cur], 1, qf, l31, hi, mrun, lrun, o0, o1);
      } else {
        attn_step<true>(kls[cur], vls[cur], 0, qf, l31, hi, mrun, lrun, o0, o1);
      }
    }
    __syncthreads();
  }

  if (active && qidx < SEQ) {
    const int b = bh / NHEAD, h = bh % NHEAD;
    const float inv = 1.f / lrun;
    __bf16* base = ao + ((size_t)b * SEQ + qidx) * DMODEL + h * HDIM + hi * 4;
    #pragma unroll
    for (int t = 0; t < 2; ++t) {
      const f32x16& o = t ? o1 : o0;
      #pragma unroll
      for (int g = 0; g < 4; ++g) {
        bf16x4 w;
        #pragma unroll
        for (int u = 0; u < 4; ++u) w[u] = (__bf16)(o[g * 4 + u] * inv);
        *(bf16x4*)(base + t * 32 + g * 8) = w;
      }
    }
  }
}

// ---------------- launcher ----------------
extern "C" void kernel_launch(void* const* d_in, const int* in_sizes, int n_in,
                              void* d_out, int out_size, void* d_ws, size_t ws_size,
                              hipStream_t stream) {
  const float* x  = (const float*)d_in[0];
  const float* Wk = (const float*)d_in[1];
  const float* bk = (const float*)d_in[2];
  const float* Wq = (const float*)d_in[3];
  const float* bq = (const float*)d_in[4];
  const float* Wv = (const float*)d_in[5];
  const float* bv = (const float*)d_in[6];
  const float* Wp = (const float*)d_in[7];
  const float* bp = (const float*)d_in[8];
  float* out = (float*)d_out;

  if (ws_size < WS_NEEDED) return;

  char* ws = (char*)d_ws;
  __bf16* xb  = (__bf16*)(ws + XB_OFF);
  __bf16* wqb = (__bf16*)(ws + WQB_OFF);   // stacked Wq|Wk|Wv|Wp
  __bf16* wpb = (__bf16*)(ws + WPB_OFF);
  __bf16* qb  = (__bf16*)(ws + QB_OFF);
  __bf16* kb  = (__bf16*)(ws + KB_OFF);
  __bf16* vtb = (__bf16*)(ws + VT_OFF);
  __bf16* ab  = (__bf16*)(ws + AO_OFF);    // aliases xb

  // zero V^T (incl. padded tail columns 1025..1055 -> exact 0 * 0 in PV, no NaN;
  // also the region K-tail staging overruns into)
  hipMemsetAsync(vtb, 0, VT_SZ, stream);

  {
    const int n_src = MTOT * DMODEL, n_dst = MPAD * DMODEL;
    convert_f32_bf16<<<dim3((n_dst / 4 + 255) / 256), dim3(256), 0, stream>>>(x, xb, n_src, n_dst);
    const int nw = DMODEL * DMODEL;
    convert_w4<<<dim3((nw / 4 + 255) / 256, 4), dim3(256), 0, stream>>>(Wq, Wk, Wv, Wp, wqb);
  }

  // fused QKV GEMM: 65 m-blocks x 18 stacked-n-blocks = 1170
  gemm_qkv_kernel<<<dim3(1170), dim3(256), 0, stream>>>(
      xb, wqb, bq, bk, bv, qb, kb, vtb);

  attn_kernel<<<dim3(8 * (BHTOT / 8) * 5), dim3(512), 0, stream>>>(qb, kb, vtb, ab);

  // projection GEMM: 65 x 6 = 390
  gemm_proj_kernel<<<dim3(390), dim3(256), 0, stream>>>(ab, wpb, bp, out);
}

// Round 11
// 176.249 us; speedup vs baseline: 1.3133x; 1.0003x over previous
//
#include <hip/hip_runtime.h>
#include <stdint.h>

// ---------------- problem constants ----------------
#define BATCH  8
#define SEQ    1025
#define DMODEL 768
#define NHEAD  12
#define HDIM   64
#define MTOT   (BATCH * SEQ)   // 8200 tokens
#define MPAD   8320            // 65 * 128
#define SPAD   1056            // 33 * 32 (padded key length, zero-filled)
#define BHTOT  (BATCH * NHEAD) // 96
#define QT32   33              // ceil(1025/32) q-tiles of 32
#define NTILE  17              // ceil(1025/64) KV tiles of 64
#define NKSTEP 12              // DMODEL / 64
#define QKSCALE 0.18033688011112042f   // 0.125 * log2(e) -> exp2-domain softmax

typedef __bf16 bf16x8 __attribute__((ext_vector_type(8)));
typedef __bf16 bf16x4 __attribute__((ext_vector_type(4)));
typedef float  f32x4  __attribute__((ext_vector_type(4)));
typedef float  f32x16 __attribute__((ext_vector_type(16)));

#if __has_builtin(__builtin_amdgcn_exp2f)
#define EXP2F __builtin_amdgcn_exp2f
#else
#define EXP2F exp2f
#endif

// ---------------- workspace layout (bytes) ----------------
constexpr size_t XB_OFF  = 0;
constexpr size_t XB_SZ   = (size_t)MPAD * DMODEL * 2;
constexpr size_t W_SZ    = (size_t)DMODEL * DMODEL * 2;
constexpr size_t WQB_OFF = XB_OFF + XB_SZ;                  // Wq,Wk,Wv,Wp contiguous (stacked)
constexpr size_t WKB_OFF = WQB_OFF + W_SZ;
constexpr size_t WVB_OFF = WKB_OFF + W_SZ;
constexpr size_t WPB_OFF = WVB_OFF + W_SZ;
constexpr size_t QB_OFF  = WPB_OFF + W_SZ;
constexpr size_t QB_SZ   = (size_t)BHTOT * SEQ * HDIM * 2;
constexpr size_t KB_OFF  = QB_OFF + QB_SZ;
constexpr size_t VT_OFF  = KB_OFF + QB_SZ;                  // K-tail overrun lands here (zeros)
constexpr size_t VT_SZ   = (size_t)BHTOT * HDIM * SPAD * 2;
constexpr size_t AO_OFF  = XB_OFF;                          // alias: xb consumed before attn writes
constexpr size_t WS_NEEDED = VT_OFF + VT_SZ;

// ---------------- helpers ----------------
__device__ __forceinline__ void async16(const void* g, void* l) {
  __builtin_amdgcn_global_load_lds((__attribute__((address_space(1))) void*)g,
                                   (__attribute__((address_space(3))) void*)l,
                                   16, 0, 0);
}

// pack two f32 -> bf16x2 dword (lo = first arg); compiler emits cvt_pk.
__device__ __forceinline__ unsigned pkbf(float lo, float hi) {
  __bf16 l = (__bf16)lo, h = (__bf16)hi;
  unsigned short lb = __builtin_bit_cast(unsigned short, l);
  unsigned short hb = __builtin_bit_cast(unsigned short, h);
  return ((unsigned)hb << 16) | (unsigned)lb;
}
__device__ __forceinline__ unsigned shfl32u(unsigned x) {   // partner half's value
  return (unsigned)__shfl_xor((int)x, 32, 64);
}
__device__ __forceinline__ float pairmax(float x) {  // max(own, lane^32)
  return fmaxf(x, __shfl_xor(x, 32, 64));
}
__device__ __forceinline__ float pairsum(float x) {  // own + lane^32
  return x + __shfl_xor(x, 32, 64);
}

// balanced trees (fp not reassociable by compiler without fast-math)
__device__ __forceinline__ float tree_max16(const f32x16& s) {
  float a0 = fmaxf(s[0], s[1]),   a1 = fmaxf(s[2], s[3]);
  float a2 = fmaxf(s[4], s[5]),   a3 = fmaxf(s[6], s[7]);
  float a4 = fmaxf(s[8], s[9]),   a5 = fmaxf(s[10], s[11]);
  float a6 = fmaxf(s[12], s[13]), a7 = fmaxf(s[14], s[15]);
  float b0 = fmaxf(a0, a1), b1 = fmaxf(a2, a3);
  float b2 = fmaxf(a4, a5), b3 = fmaxf(a6, a7);
  return fmaxf(fmaxf(b0, b1), fmaxf(b2, b3));
}
__device__ __forceinline__ float tree_sum16(const f32x16& s) {
  float a0 = s[0] + s[1],   a1 = s[2] + s[3];
  float a2 = s[4] + s[5],   a3 = s[6] + s[7];
  float a4 = s[8] + s[9],   a5 = s[10] + s[11];
  float a6 = s[12] + s[13], a7 = s[14] + s[15];
  float b0 = a0 + a1, b1 = a2 + a3, b2 = a4 + a5, b3 = a6 + a7;
  return (b0 + b1) + (b2 + b3);
}

// ---------------- fp32 -> bf16 conversion (zero-fills dst beyond n_src) ----------------
__global__ void __launch_bounds__(256)
convert_f32_bf16(const float* __restrict__ src, __bf16* __restrict__ dst,
                 int n_src, int n_dst) {
  int idx = (blockIdx.x * 256 + threadIdx.x) * 4;
  if (idx >= n_dst) return;
  bf16x4 o;
  if (idx + 3 < n_src) {
    float4 v = *(const float4*)&src[idx];
    o[0] = (__bf16)v.x; o[1] = (__bf16)v.y; o[2] = (__bf16)v.z; o[3] = (__bf16)v.w;
  } else {
    #pragma unroll
    for (int t = 0; t < 4; ++t) {
      int k = idx + t;
      o[t] = (k < n_src) ? (__bf16)src[k] : (__bf16)0.f;
    }
  }
  *(bf16x4*)&dst[idx] = o;
}

// 4 weight matrices in one launch; dst regions are contiguous (WQB..WPB).
__global__ void __launch_bounds__(256)
convert_w4(const float* __restrict__ w0, const float* __restrict__ w1,
           const float* __restrict__ w2, const float* __restrict__ w3,
           __bf16* __restrict__ dst) {
  const int which = blockIdx.y;
  const float* src = (which == 0) ? w0 : (which == 1) ? w1 : (which == 2) ? w2 : w3;
  __bf16* d = dst + (size_t)which * DMODEL * DMODEL;
  int idx = (blockIdx.x * 256 + threadIdx.x) * 4;
  if (idx >= DMODEL * DMODEL) return;
  float4 v = *(const float4*)&src[idx];
  bf16x4 o;
  o[0] = (__bf16)v.x; o[1] = (__bf16)v.y; o[2] = (__bf16)v.z; o[3] = (__bf16)v.w;
  *(bf16x4*)&d[idx] = o;
}

// ---------------- shared 128x128 GEMM core: C = A @ W^T ----------------
// T2 both-sides swizzle (r10, conflicts 1.1e7 -> 0) + T3 minimum-2-phase double
// buffer (r11): prologue stages tile 0; each K-step issues the NEXT tile's
// global_load_lds into buf^1 BEFORE computing buf[cur], so the load latency
// (~200-600 cyc L2) hides under ds_read+MFMA (~300 cyc). One barrier per step
// (compiler's vmcnt(0)+lgkmcnt(0) drain at the barrier covers both buffers'
// hazards: stage-complete for cur^1, reads-done for the buffer about to be
// overwritten next step). LDS 64 KB -> 2 blocks/CU.
__device__ __forceinline__ void stage_tile(const __bf16* __restrict__ A,
                                           const __bf16* __restrict__ W,
                                           __bf16* As, __bf16* Bs,
                                           int m0, int n0, int kt, int tid) {
  #pragma unroll
  for (int i = 0; i < 4; ++i) {
    const int gi = i * 256 + tid;      // granule index 0..1023 (16 B granules)
    const int r  = gi >> 3;            // tile row 0..127
    const int p  = gi & 7;             // LDS granule within row (linear dest)
    const int g  = p ^ (r & 7);        // inverse-swizzled SOURCE granule
    async16(A + (size_t)(m0 + r) * DMODEL + kt + g * 8, As + gi * 8);
    async16(W + (size_t)(n0 + r) * DMODEL + kt + g * 8, Bs + gi * 8);
  }
}

__device__ __forceinline__ void compute_tile(const __bf16* __restrict__ As,
                                             const __bf16* __restrict__ Bs,
                                             f32x4 acc[4][4],
                                             int wm, int wn, int l15, int lg, int rx) {
  #pragma unroll
  for (int kk = 0; kk < 2; ++kk) {
    bf16x8 af[4], bfr[4];
    #pragma unroll
    for (int i = 0; i < 4; ++i)
      af[i] = *(const bf16x8*)&As[(wm * 64 + i * 16 + l15) * 64 + (((kk * 4 + lg) ^ rx)) * 8];
    #pragma unroll
    for (int j = 0; j < 4; ++j)
      bfr[j] = *(const bf16x8*)&Bs[(wn * 64 + j * 16 + l15) * 64 + (((kk * 4 + lg) ^ rx)) * 8];
    #pragma unroll
    for (int i = 0; i < 4; ++i)
      #pragma unroll
      for (int j = 0; j < 4; ++j)
        acc[i][j] = __builtin_amdgcn_mfma_f32_16x16x32_bf16(af[i], bfr[j], acc[i][j], 0, 0, 0);
  }
}

__device__ __forceinline__ void gemm_core(const __bf16* __restrict__ A,
                                          const __bf16* __restrict__ W,
                                          __bf16 (*As)[128 * 64], __bf16 (*Bs)[128 * 64],
                                          int m0, int n0, f32x4 acc[4][4]) {
  const int tid  = threadIdx.x;
  const int lane = tid & 63;
  const int wave = tid >> 6;
  const int wm = wave >> 1, wn = wave & 1;
  const int l15 = lane & 15, lg = lane >> 4;
  const int rx  = l15 & 7;               // read-side XOR key (row & 7)

  stage_tile(A, W, As[0], Bs[0], m0, n0, 0, tid);
  __syncthreads();                       // tile 0 ready

  for (int t = 0; t < NKSTEP; ++t) {
    const int cur = t & 1;
    if (t + 1 < NKSTEP)
      stage_tile(A, W, As[cur ^ 1], Bs[cur ^ 1], m0, n0, (t + 1) * 64, tid);
    compute_tile(As[cur], Bs[cur], acc, wm, wn, l15, lg, rx);
    __syncthreads();                     // stage drained + WAR for next overwrite
  }
}

// ---------------- fused QKV projection: one GEMM vs stacked W [2304][768] ----------------
// Grid: 1170 blocks (65 m x 18 n), XCD-partitioned along m (bijective, q=146,r=2).
__global__ void __launch_bounds__(256)
gemm_qkv_kernel(const __bf16* __restrict__ xb, const __bf16* __restrict__ wsb,
                const float* __restrict__ bq, const float* __restrict__ bk,
                const float* __restrict__ bv,
                __bf16* __restrict__ qb, __bf16* __restrict__ kb,
                __bf16* __restrict__ vtb) {
  __shared__ __bf16 As[2][128 * 64];
  __shared__ __bf16 Bs[2][128 * 64];
  const int wg  = blockIdx.x;
  const int xcd = wg & 7, idx = wg >> 3;
  const int v   = xcd * 146 + (xcd < 2 ? xcd : 2) + idx;   // bijective virtual index
  const int m0  = (v / 18) * 128;
  const int n0  = (v % 18) * 128;                          // 0..2176 in stacked-N

  f32x4 acc[4][4];
  #pragma unroll
  for (int i = 0; i < 4; ++i)
    #pragma unroll
    for (int j = 0; j < 4; ++j) acc[i][j] = (f32x4){0.f, 0.f, 0.f, 0.f};

  gemm_core(xb, wsb, As, Bs, m0, n0, acc);

  const int lane = threadIdx.x & 63;
  const int wave = threadIdx.x >> 6;
  const int wm = wave >> 1, wn = wave & 1;
  const int l15 = lane & 15, lg = lane >> 4;
  #pragma unroll
  for (int i = 0; i < 4; ++i) {
    #pragma unroll
    for (int j = 0; j < 4; ++j) {
      const int ncolg = n0 + wn * 64 + j * 16 + l15;       // 0..2303
      // 768 % 16 == 0 -> all 16 lanes of a j-iter share one mode (wave-uniform branch)
      const int mode = ncolg / 768;
      const int col  = ncolg - mode * 768;
      const float bb = (mode == 0 ? bq : (mode == 1 ? bk : bv))[col];
      const int h = col >> 6, hd = col & 63;
      #pragma unroll
      for (int r = 0; r < 4; ++r) {
        const int mrow = m0 + wm * 64 + i * 16 + lg * 4 + r;
        if (mrow < MTOT) {
          float val = acc[i][j][r] + bb;
          const int b = mrow / SEQ;
          const int s = mrow - b * SEQ;
          const int bh = b * NHEAD + h;
          if (mode == 2)
            vtb[((size_t)bh * HDIM + hd) * SPAD + s] = (__bf16)val;
          else if (mode == 0)
            qb[((size_t)bh * SEQ + s) * HDIM + hd] = (__bf16)(val * QKSCALE);
          else
            kb[((size_t)bh * SEQ + s) * HDIM + hd] = (__bf16)val;
        }
      }
    }
  }
}

// ---------------- output projection (m-partitioned XCD swizzle, NB=390: q=48,r=6) ----
__global__ void __launch_bounds__(256)
gemm_proj_kernel(const __bf16* __restrict__ ab, const __bf16* __restrict__ wpb,
                 const float* __restrict__ bp, float* __restrict__ out) {
  __shared__ __bf16 As[2][128 * 64];
  __shared__ __bf16 Bs[2][128 * 64];
  const int wg  = blockIdx.x;
  const int xcd = wg & 7, idx = wg >> 3;
  const int v   = xcd * 48 + (xcd < 6 ? xcd : 6) + idx;
  const int m0  = (v / 6) * 128;
  const int n0  = (v % 6) * 128;

  f32x4 acc[4][4];
  #pragma unroll
  for (int i = 0; i < 4; ++i)
    #pragma unroll
    for (int j = 0; j < 4; ++j) acc[i][j] = (f32x4){0.f, 0.f, 0.f, 0.f};

  gemm_core(ab, wpb, As, Bs, m0, n0, acc);

  const int lane = threadIdx.x & 63;
  const int wave = threadIdx.x >> 6;
  const int wm = wave >> 1, wn = wave & 1;
  const int l15 = lane & 15, lg = lane >> 4;
  #pragma unroll
  for (int i = 0; i < 4; ++i) {
    #pragma unroll
    for (int j = 0; j < 4; ++j) {
      const int ncol = n0 + wn * 64 + j * 16 + l15;
      const float bb = bp[ncol];
      #pragma unroll
      for (int r = 0; r < 4; ++r) {
        const int mrow = m0 + wm * 64 + i * 16 + lg * 4 + r;
        if (mrow < MTOT) out[(size_t)mrow * DMODEL + ncol] = acc[i][j][r] + bb;
      }
    }
  }
}

// ---------------- flash attention: 8-wave blocks, LDS-staged K/V, swizzled reads ----
// (unchanged from Round 8 — see that round's notes)
__device__ __forceinline__ void build_pa(const f32x16& s, int hi, bf16x8 pa[2]) {
  #pragma unroll
  for (int sl2 = 0; sl2 < 2; ++sl2) {
    const int off = sl2 * 8;
    unsigned w0 = pkbf(s[off + 0], s[off + 1]);
    unsigned w1 = pkbf(s[off + 2], s[off + 3]);
    unsigned w2 = pkbf(s[off + 4], s[off + 5]);
    unsigned w3 = pkbf(s[off + 6], s[off + 7]);
    unsigned p0 = shfl32u(w0), p1 = shfl32u(w1);
    unsigned p2 = shfl32u(w2), p3 = shfl32u(w3);
    unsigned pw[4];
    pw[0] = hi ? p2 : w0;
    pw[1] = hi ? p3 : w1;
    pw[2] = hi ? w2 : p0;
    pw[3] = hi ? w3 : p1;
    __builtin_memcpy(&pa[sl2], pw, 16);
  }
}

__device__ __forceinline__ void stage_kv(const __bf16* __restrict__ Kp,
                                         const __bf16* __restrict__ Vp,
                                         __bf16* kls, __bf16* vls,
                                         int k0, int tid) {
  const int r = tid >> 3, p = tid & 7;
  const int g = p ^ (r & 7);
  async16(Kp + (size_t)(k0 + r) * HDIM + g * 8, kls + tid * 8);
  int col = k0 + g * 8;
  if (col >= SPAD) col = 0;
  async16(Vp + (size_t)r * SPAD + col, vls + tid * 8);
}

template<bool MASK>
__device__ __forceinline__ void attn_step(const __bf16* __restrict__ kls,
                                          const __bf16* __restrict__ vls,
                                          int half, const bf16x8 (&qf)[4],
                                          int l31, int hi,
                                          float& mrun, float& lrun,
                                          f32x16& o0, f32x16& o1) {
  const int kr = half * 32 + l31;
  const int krx = kr & 7;

  f32x16 s;
  #pragma unroll
  for (int r = 0; r < 16; ++r) s[r] = 0.f;
  #pragma unroll
  for (int sl = 0; sl < 4; ++sl) {
    bf16x8 kf = *(const bf16x8*)&kls[(kr * 8 + ((2 * sl + hi) ^ krx)) * 8];
    s = __builtin_amdgcn_mfma_f32_32x32x16_bf16(kf, qf[sl], s, 0, 0, 0);
  }
  if (MASK) {
    #pragma unroll
    for (int r = 1; r < 16; ++r) s[r] = -1e30f;
    if (hi) s[0] = -1e30f;
  }

  const float mloc = pairmax(tree_max16(s));
  if (!__all(mloc - mrun <= 8.f)) {   // defer-max (T13)
    const float mnew = fmaxf(mrun, mloc);
    const float corr = EXP2F(mrun - mnew);
    lrun *= corr;
    #pragma unroll
    for (int r = 0; r < 16; ++r) { o0[r] *= corr; o1[r] *= corr; }
    mrun = mnew;
  }

  #pragma unroll
  for (int r = 0; r < 16; ++r) s[r] = EXP2F(s[r] - mrun);
  lrun += pairsum(tree_sum16(s));

  bf16x8 pa[2];
  build_pa(s, hi, pa);

  #pragma unroll
  for (int ot = 0; ot < 2; ++ot) {
    const int vr = ot * 32 + l31;
    const int vrx = vr & 7;
    f32x16& o = ot ? o1 : o0;
    #pragma unroll
    for (int j = 0; j < 2; ++j) {
      bf16x8 vf = *(const bf16x8*)&vls[(vr * 8 + ((half * 4 + 2 * j + hi) ^ vrx)) * 8];
      o = __builtin_amdgcn_mfma_f32_32x32x16_bf16(vf, pa[j], o, 0, 0, 0);
    }
  }
}

__global__ void __launch_bounds__(512, 4)
attn_kernel(const __bf16* __restrict__ qb, const __bf16* __restrict__ kb,
            const __bf16* __restrict__ vtb, __bf16* __restrict__ ao) {
  __shared__ __bf16 kls[2][64 * 64];
  __shared__ __bf16 vls[2][64 * 64];

  const int tid  = threadIdx.x;
  const int wid  = tid >> 6;
  const int lane = tid & 63;
  const int l31 = lane & 31, hi = (lane >> 5) & 1;

  const int bid = blockIdx.x;
  const int xcd = bid & 7;
  const int ixd = bid >> 3;
  const int bh  = xcd * (BHTOT / 8) + ixd / 5;
  const int qblk = ixd % 5;
  const int qt  = qblk * 8 + wid;
  const bool active = qt < QT32;

  const __bf16* Qp = qb + (size_t)bh * SEQ * HDIM;
  const __bf16* Kp = kb + (size_t)bh * SEQ * HDIM;
  const __bf16* Vp = vtb + (size_t)bh * HDIM * SPAD;

  const int qidx = qt * 32 + l31;
  const int qc = (qidx < SEQ ? qidx : SEQ - 1);
  bf16x8 qf[4];
  if (active) {
    #pragma unroll
    for (int sl = 0; sl < 4; ++sl)
      qf[sl] = *(const bf16x8*)&Qp[(size_t)qc * HDIM + sl * 16 + hi * 8];
  }

  f32x16 o0, o1;
  #pragma unroll
  for (int r = 0; r < 16; ++r) { o0[r] = 0.f; o1[r] = 0.f; }
  float mrun = -1e30f, lrun = 0.f;

  stage_kv(Kp, Vp, kls[0], vls[0], 0, tid);
  __syncthreads();

  for (int t = 0; t < NTILE; ++t) {
    const int cur = t & 1;
    if (t + 1 < NTILE)
      stage_kv(Kp, Vp, kls[cur ^ 1], vls[cur ^ 1], (t + 1) * 64, tid);
    if (active) {
      if (t < NTILE - 1) {
        attn_step<false>(kls[cur], vls[cur], 0, qf, l31, hi, mrun, lrun, o0, o1);
        attn_step<false>(kls[cur], vls[cur], 1, qf, l31, hi, mrun, lrun, o0, o1);
      } else {
        attn_step<true>(kls[cur], vls[cur], 0, qf, l31, hi, mrun, lrun, o0, o1);
      }
    }
    __syncthreads();
  }

  if (active && qidx < SEQ) {
    const int b = bh / NHEAD, h = bh % NHEAD;
    const float inv = 1.f / lrun;
    __bf16* base = ao + ((size_t)b * SEQ + qidx) * DMODEL + h * HDIM + hi * 4;
    #pragma unroll
    for (int t = 0; t < 2; ++t) {
      const f32x16& o = t ? o1 : o0;
      #pragma unroll
      for (int g = 0; g < 4; ++g) {
        bf16x4 w;
        #pragma unroll
        for (int u = 0; u < 4; ++u) w[u] = (__bf16)(o[g * 4 + u] * inv);
        *(bf16x4*)(base + t * 32 + g * 8) = w;
      }
    }
  }
}

// ---------------- launcher ----------------
extern "C" void kernel_launch(void* const* d_in, const int* in_sizes, int n_in,
                              void* d_out, int out_size, void* d_ws, size_t ws_size,
                              hipStream_t stream) {
  const float* x  = (const float*)d_in[0];
  const float* Wk = (const float*)d_in[1];
  const float* bk = (const float*)d_in[2];
  const float* Wq = (const float*)d_in[3];
  const float* bq = (const float*)d_in[4];
  const float* Wv = (const float*)d_in[5];
  const float* bv = (const float*)d_in[6];
  const float* Wp = (const float*)d_in[7];
  const float* bp = (const float*)d_in[8];
  float* out = (float*)d_out;

  if (ws_size < WS_NEEDED) return;

  char* ws = (char*)d_ws;
  __bf16* xb  = (__bf16*)(ws + XB_OFF);
  __bf16* wqb = (__bf16*)(ws + WQB_OFF);   // stacked Wq|Wk|Wv|Wp
  __bf16* wpb = (__bf16*)(ws + WPB_OFF);
  __bf16* qb  = (__bf16*)(ws + QB_OFF);
  __bf16* kb  = (__bf16*)(ws + KB_OFF);
  __bf16* vtb = (__bf16*)(ws + VT_OFF);
  __bf16* ab  = (__bf16*)(ws + AO_OFF);    // aliases xb

  // zero V^T (incl. padded tail columns 1025..1055 -> exact 0 * 0 in PV, no NaN;
  // also the region K-tail staging overruns into)
  hipMemsetAsync(vtb, 0, VT_SZ, stream);

  {
    const int n_src = MTOT * DMODEL, n_dst = MPAD * DMODEL;
    convert_f32_bf16<<<dim3((n_dst / 4 + 255) / 256), dim3(256), 0, stream>>>(x, xb, n_src, n_dst);
    const int nw = DMODEL * DMODEL;
    convert_w4<<<dim3((nw / 4 + 255) / 256, 4), dim3(256), 0, stream>>>(Wq, Wk, Wv, Wp, wqb);
  }

  // fused QKV GEMM: 65 m-blocks x 18 stacked-n-blocks = 1170
  gemm_qkv_kernel<<<dim3(1170), dim3(256), 0, stream>>>(
      xb, wqb, bq, bk, bv, qb, kb, vtb);

  attn_kernel<<<dim3(8 * (BHTOT / 8) * 5), dim3(512), 0, stream>>>(qb, kb, vtb, ab);

  // projection GEMM: 65 x 6 = 390
  gemm_proj_kernel<<<dim3(390), dim3(256), 0, stream>>>(ab, wpb, bp, out);
}

// Round 14
// 171.834 us; speedup vs baseline: 1.3471x; 1.0257x over previous
//
#include <hip/hip_runtime.h>
#include <stdint.h>

// ---------------- problem constants ----------------
#define BATCH  8
#define SEQ    1025
#define DMODEL 768
#define NHEAD  12
#define HDIM   64
#define MTOT   (BATCH * SEQ)   // 8200 tokens
#define MPAD   8320            // 65 * 128
#define SPAD   1056            // 33 * 32 (padded key length, zero-filled)
#define BHTOT  (BATCH * NHEAD) // 96
#define QT32   33              // ceil(1025/32) q-tiles of 32
#define NTILE  17              // ceil(1025/64) KV tiles of 64
#define NKSTEP 12              // DMODEL / 64
#define QKSCALE 0.18033688011112042f   // 0.125 * log2(e) -> exp2-domain softmax

typedef __bf16 bf16x8 __attribute__((ext_vector_type(8)));
typedef __bf16 bf16x4 __attribute__((ext_vector_type(4)));
typedef float  f32x4  __attribute__((ext_vector_type(4)));
typedef float  f32x16 __attribute__((ext_vector_type(16)));

#if __has_builtin(__builtin_amdgcn_exp2f)
#define EXP2F __builtin_amdgcn_exp2f
#else
#define EXP2F exp2f
#endif

// ---------------- workspace layout (bytes) ----------------
constexpr size_t XB_OFF  = 0;
constexpr size_t XB_SZ   = (size_t)MPAD * DMODEL * 2;
constexpr size_t W_SZ    = (size_t)DMODEL * DMODEL * 2;
constexpr size_t WQB_OFF = XB_OFF + XB_SZ;                  // Wq,Wk,Wv,Wp contiguous (stacked)
constexpr size_t WKB_OFF = WQB_OFF + W_SZ;
constexpr size_t WVB_OFF = WKB_OFF + W_SZ;
constexpr size_t WPB_OFF = WVB_OFF + W_SZ;
constexpr size_t QB_OFF  = WPB_OFF + W_SZ;
constexpr size_t QB_SZ   = (size_t)BHTOT * SEQ * HDIM * 2;
constexpr size_t KB_OFF  = QB_OFF + QB_SZ;
constexpr size_t VT_OFF  = KB_OFF + QB_SZ;                  // K-tail overrun lands here (zeros)
constexpr size_t VT_SZ   = (size_t)BHTOT * HDIM * SPAD * 2;
constexpr size_t AO_OFF  = XB_OFF;                          // alias: xb consumed before attn writes
constexpr size_t WS_NEEDED = VT_OFF + VT_SZ;

// ---------------- helpers ----------------
__device__ __forceinline__ void async16(const void* g, void* l) {
  __builtin_amdgcn_global_load_lds((__attribute__((address_space(1))) void*)g,
                                   (__attribute__((address_space(3))) void*)l,
                                   16, 0, 0);
}

// pack two f32 -> bf16x2 dword (lo = first arg); compiler emits cvt_pk.
__device__ __forceinline__ unsigned pkbf(float lo, float hi) {
  __bf16 l = (__bf16)lo, h = (__bf16)hi;
  unsigned short lb = __builtin_bit_cast(unsigned short, l);
  unsigned short hb = __builtin_bit_cast(unsigned short, h);
  return ((unsigned)hb << 16) | (unsigned)lb;
}
__device__ __forceinline__ unsigned shfl32u(unsigned x) {   // partner half's value
  return (unsigned)__shfl_xor((int)x, 32, 64);
}
__device__ __forceinline__ float pairmax(float x) {  // max(own, lane^32)
  return fmaxf(x, __shfl_xor(x, 32, 64));
}
__device__ __forceinline__ float pairsum(float x) {  // own + lane^32
  return x + __shfl_xor(x, 32, 64);
}

// balanced trees (fp not reassociable by compiler without fast-math)
__device__ __forceinline__ float tree_max16(const f32x16& s) {
  float a0 = fmaxf(s[0], s[1]),   a1 = fmaxf(s[2], s[3]);
  float a2 = fmaxf(s[4], s[5]),   a3 = fmaxf(s[6], s[7]);
  float a4 = fmaxf(s[8], s[9]),   a5 = fmaxf(s[10], s[11]);
  float a6 = fmaxf(s[12], s[13]), a7 = fmaxf(s[14], s[15]);
  float b0 = fmaxf(a0, a1), b1 = fmaxf(a2, a3);
  float b2 = fmaxf(a4, a5), b3 = fmaxf(a6, a7);
  return fmaxf(fmaxf(b0, b1), fmaxf(b2, b3));
}
__device__ __forceinline__ float tree_sum16(const f32x16& s) {
  float a0 = s[0] + s[1],   a1 = s[2] + s[3];
  float a2 = s[4] + s[5],   a3 = s[6] + s[7];
  float a4 = s[8] + s[9],   a5 = s[10] + s[11];
  float a6 = s[12] + s[13], a7 = s[14] + s[15];
  float b0 = a0 + a1, b1 = a2 + a3, b2 = a4 + a5, b3 = a6 + a7;
  return (b0 + b1) + (b2 + b3);
}

// ---------------- fp32 -> bf16 conversion (zero-fills dst beyond n_src) ----------------
__global__ void __launch_bounds__(256)
convert_f32_bf16(const float* __restrict__ src, __bf16* __restrict__ dst,
                 int n_src, int n_dst) {
  int idx = (blockIdx.x * 256 + threadIdx.x) * 4;
  if (idx >= n_dst) return;
  bf16x4 o;
  if (idx + 3 < n_src) {
    float4 v = *(const float4*)&src[idx];
    o[0] = (__bf16)v.x; o[1] = (__bf16)v.y; o[2] = (__bf16)v.z; o[3] = (__bf16)v.w;
  } else {
    #pragma unroll
    for (int t = 0; t < 4; ++t) {
      int k = idx + t;
      o[t] = (k < n_src) ? (__bf16)src[k] : (__bf16)0.f;
    }
  }
  *(bf16x4*)&dst[idx] = o;
}

// 4 weight matrices in one launch; dst regions are contiguous (WQB..WPB).
__global__ void __launch_bounds__(256)
convert_w4(const float* __restrict__ w0, const float* __restrict__ w1,
           const float* __restrict__ w2, const float* __restrict__ w3,
           __bf16* __restrict__ dst) {
  const int which = blockIdx.y;
  const float* src = (which == 0) ? w0 : (which == 1) ? w1 : (which == 2) ? w2 : w3;
  __bf16* d = dst + (size_t)which * DMODEL * DMODEL;
  int idx = (blockIdx.x * 256 + threadIdx.x) * 4;
  if (idx >= DMODEL * DMODEL) return;
  float4 v = *(const float4*)&src[idx];
  bf16x4 o;
  o[0] = (__bf16)v.x; o[1] = (__bf16)v.y; o[2] = (__bf16)v.z; o[3] = (__bf16)v.w;
  *(bf16x4*)&d[idx] = o;
}

// ---------------- shared 128x128 GEMM core: C = A @ W^T ----------------
// r10: T2 both-sides swizzle (conflicts 1.1e7 -> 0).
// r12: T4 counted-vmcnt pipeline -- the __syncthreads drain (vmcnt(0) incl.
// just-issued loads) exposed full load latency every step (r11 null).
// Now: stage(t+1) -> vmcnt(8) (waits ONLY stage(t)) -> s_barrier -> compute(t)
// -> s_barrier. K-loop unrolled x2 so buffer indices are static (rule #20).
// Addressing strength-reduced: ds_read offsets fold to base+imm; staging
// pointers advance by constant stride.
__device__ __forceinline__ void stage_step(const __bf16* const (&sa)[4],
                                           const __bf16* const (&sw)[4],
                                           __bf16* As, __bf16* Bs,
                                           int kt, int tid) {
  #pragma unroll
  for (int i = 0; i < 4; ++i) {
    const int gi = i * 256 + tid;
    async16(sa[i] + kt, As + gi * 8);
    async16(sw[i] + kt, Bs + gi * 8);
  }
}

__device__ __forceinline__ void compute_tile(const __bf16* __restrict__ pa,
                                             const __bf16* __restrict__ pb,
                                             int off0, int off1,
                                             f32x4 acc[4][4]) {
  #pragma unroll
  for (int kk = 0; kk < 2; ++kk) {
    const int offk = kk ? off1 : off0;
    bf16x8 af[4], bfr[4];
    #pragma unroll
    for (int i = 0; i < 4; ++i)
      af[i] = *(const bf16x8*)(pa + i * 1024 + offk);      // i*16 rows * 64/row
    #pragma unroll
    for (int j = 0; j < 4; ++j)
      bfr[j] = *(const bf16x8*)(pb + j * 1024 + offk);
    __builtin_amdgcn_s_setprio(1);
    #pragma unroll
    for (int i = 0; i < 4; ++i)
      #pragma unroll
      for (int j = 0; j < 4; ++j)
        acc[i][j] = __builtin_amdgcn_mfma_f32_16x16x32_bf16(af[i], bfr[j], acc[i][j], 0, 0, 0);
    __builtin_amdgcn_s_setprio(0);
  }
}

#define GC_WAIT8  asm volatile("s_waitcnt vmcnt(8)" ::: "memory")
#define GC_WAIT0  asm volatile("s_waitcnt vmcnt(0)" ::: "memory")
#define GC_BAR    __builtin_amdgcn_s_barrier()
#define GC_SCHED  __builtin_amdgcn_sched_barrier(0)

__device__ __forceinline__ void gemm_core(const __bf16* __restrict__ A,
                                          const __bf16* __restrict__ W,
                                          __bf16 (*As)[128 * 64], __bf16 (*Bs)[128 * 64],
                                          int m0, int n0, f32x4 acc[4][4]) {
  const int tid  = threadIdx.x;
  const int lane = tid & 63;
  const int wave = tid >> 6;
  const int wm = wave >> 1, wn = wave & 1;
  const int l15 = lane & 15, lg = lane >> 4;
  const int rx  = l15 & 7;

  // staging source pointers (per thread, advance by +kt)
  const __bf16* sa[4];
  const __bf16* sw[4];
  #pragma unroll
  for (int i = 0; i < 4; ++i) {
    const int gi = i * 256 + tid;
    const int r  = gi >> 3;
    const int g  = (gi & 7) ^ (r & 7);   // inverse-swizzled source granule
    sa[i] = A + (size_t)(m0 + r) * DMODEL + g * 8;
    sw[i] = W + (size_t)(n0 + r) * DMODEL + g * 8;
  }
  // ds_read bases (element offsets; i/j add 1024*i, kk adds off0/off1)
  const int off0 = ((0 * 4 + lg) ^ rx) * 8;
  const int off1 = ((1 * 4 + lg) ^ rx) * 8;
  const __bf16* paA0 = &As[0][(wm * 64 + l15) * 64];
  const __bf16* paA1 = &As[1][(wm * 64 + l15) * 64];
  const __bf16* pbB0 = &Bs[0][(wn * 64 + l15) * 64];
  const __bf16* pbB1 = &Bs[1][(wn * 64 + l15) * 64];

  stage_step(sa, sw, As[0], Bs[0], 0, tid);

  #pragma unroll 1
  for (int tt = 0; tt < NKSTEP / 2; ++tt) {
    const int t = tt * 2;
    // --- substep A: stage(t+1)->buf1, compute buf0 ---
    stage_step(sa, sw, As[1], Bs[1], (t + 1) * 64, tid);
    GC_WAIT8;            // stage(t) landed (only the 8 new loads may remain)
    GC_BAR;              // all waves' stage(t) visible
    GC_SCHED;
    compute_tile(paA0, pbB0, off0, off1, acc);
    GC_BAR;              // buf0 reads done before it is re-staged next substep
    GC_SCHED;
    // --- substep B: stage(t+2)->buf0, compute buf1 ---
    if (t + 2 < NKSTEP) {
      stage_step(sa, sw, As[0], Bs[0], (t + 2) * 64, tid);
      GC_WAIT8;
    } else {
      GC_WAIT0;          // final tile: drain everything
    }
    GC_BAR;
    GC_SCHED;
    compute_tile(paA1, pbB1, off0, off1, acc);
    GC_BAR;
    GC_SCHED;
  }
}

// ---------------- fused QKV projection: one GEMM vs stacked W [2304][768] ----------------
// Grid: 1170 blocks (65 m x 18 n), XCD-partitioned along m (bijective, q=146,r=2).
__global__ void __launch_bounds__(256)
gemm_qkv_kernel(const __bf16* __restrict__ xb, const __bf16* __restrict__ wsb,
                const float* __restrict__ bq, const float* __restrict__ bk,
                const float* __restrict__ bv,
                __bf16* __restrict__ qb, __bf16* __restrict__ kb,
                __bf16* __restrict__ vtb) {
  __shared__ __bf16 As[2][128 * 64];
  __shared__ __bf16 Bs[2][128 * 64];
  const int wg  = blockIdx.x;
  const int xcd = wg & 7, idx = wg >> 3;
  const int v   = xcd * 146 + (xcd < 2 ? xcd : 2) + idx;   // bijective virtual index
  const int m0  = (v / 18) * 128;
  const int n0  = (v % 18) * 128;                          // 0..2176 in stacked-N

  f32x4 acc[4][4];
  #pragma unroll
  for (int i = 0; i < 4; ++i)
    #pragma unroll
    for (int j = 0; j < 4; ++j) acc[i][j] = (f32x4){0.f, 0.f, 0.f, 0.f};

  gemm_core(xb, wsb, As, Bs, m0, n0, acc);

  const int lane = threadIdx.x & 63;
  const int wave = threadIdx.x >> 6;
  const int wm = wave >> 1, wn = wave & 1;
  const int l15 = lane & 15, lg = lane >> 4;
  #pragma unroll
  for (int i = 0; i < 4; ++i) {
    #pragma unroll
    for (int j = 0; j < 4; ++j) {
      const int ncolg = n0 + wn * 64 + j * 16 + l15;       // 0..2303
      // 768 % 16 == 0 -> all 16 lanes of a j-iter share one mode (wave-uniform branch)
      const int mode = ncolg / 768;
      const int col  = ncolg - mode * 768;
      const float bb = (mode == 0 ? bq : (mode == 1 ? bk : bv))[col];
      const int h = col >> 6, hd = col & 63;
      #pragma unroll
      for (int r = 0; r < 4; ++r) {
        const int mrow = m0 + wm * 64 + i * 16 + lg * 4 + r;
        if (mrow < MTOT) {
          float val = acc[i][j][r] + bb;
          const int b = mrow / SEQ;
          const int s = mrow - b * SEQ;
          const int bh = b * NHEAD + h;
          if (mode == 2)
            vtb[((size_t)bh * HDIM + hd) * SPAD + s] = (__bf16)val;
          else if (mode == 0)
            qb[((size_t)bh * SEQ + s) * HDIM + hd] = (__bf16)(val * QKSCALE);
          else
            kb[((size_t)bh * SEQ + s) * HDIM + hd] = (__bf16)val;
        }
      }
    }
  }
}

// ---------------- output projection (m-partitioned XCD swizzle, NB=390: q=48,r=6) ----
__global__ void __launch_bounds__(256)
gemm_proj_kernel(const __bf16* __restrict__ ab, const __bf16* __restrict__ wpb,
                 const float* __restrict__ bp, float* __restrict__ out) {
  __shared__ __bf16 As[2][128 * 64];
  __shared__ __bf16 Bs[2][128 * 64];
  const int wg  = blockIdx.x;
  const int xcd = wg & 7, idx = wg >> 3;
  const int v   = xcd * 48 + (xcd < 6 ? xcd : 6) + idx;
  const int m0  = (v / 6) * 128;
  const int n0  = (v % 6) * 128;

  f32x4 acc[4][4];
  #pragma unroll
  for (int i = 0; i < 4; ++i)
    #pragma unroll
    for (int j = 0; j < 4; ++j) acc[i][j] = (f32x4){0.f, 0.f, 0.f, 0.f};

  gemm_core(ab, wpb, As, Bs, m0, n0, acc);

  const int lane = threadIdx.x & 63;
  const int wave = threadIdx.x >> 6;
  const int wm = wave >> 1, wn = wave & 1;
  const int l15 = lane & 15, lg = lane >> 4;
  #pragma unroll
  for (int i = 0; i < 4; ++i) {
    #pragma unroll
    for (int j = 0; j < 4; ++j) {
      const int ncol = n0 + wn * 64 + j * 16 + l15;
      const float bb = bp[ncol];
      #pragma unroll
      for (int r = 0; r < 4; ++r) {
        const int mrow = m0 + wm * 64 + i * 16 + lg * 4 + r;
        if (mrow < MTOT) out[(size_t)mrow * DMODEL + ncol] = acc[i][j][r] + bb;
      }
    }
  }
}

// ---------------- flash attention: 8-wave blocks, LDS-staged K/V, swizzled reads ----
// (unchanged from Round 8 — see that round's notes)
__device__ __forceinline__ void build_pa(const f32x16& s, int hi, bf16x8 pa[2]) {
  #pragma unroll
  for (int sl2 = 0; sl2 < 2; ++sl2) {
    const int off = sl2 * 8;
    unsigned w0 = pkbf(s[off + 0], s[off + 1]);
    unsigned w1 = pkbf(s[off + 2], s[off + 3]);
    unsigned w2 = pkbf(s[off + 4], s[off + 5]);
    unsigned w3 = pkbf(s[off + 6], s[off + 7]);
    unsigned p0 = shfl32u(w0), p1 = shfl32u(w1);
    unsigned p2 = shfl32u(w2), p3 = shfl32u(w3);
    unsigned pw[4];
    pw[0] = hi ? p2 : w0;
    pw[1] = hi ? p3 : w1;
    pw[2] = hi ? w2 : p0;
    pw[3] = hi ? w3 : p1;
    __builtin_memcpy(&pa[sl2], pw, 16);
  }
}

__device__ __forceinline__ void stage_kv(const __bf16* __restrict__ Kp,
                                         const __bf16* __restrict__ Vp,
                                         __bf16* kls, __bf16* vls,
                                         int k0, int tid) {
  const int r = tid >> 3, p = tid & 7;
  const int g = p ^ (r & 7);
  async16(Kp + (size_t)(k0 + r) * HDIM + g * 8, kls + tid * 8);
  int col = k0 + g * 8;
  if (col >= SPAD) col = 0;
  async16(Vp + (size_t)r * SPAD + col, vls + tid * 8);
}

template<bool MASK>
__device__ __forceinline__ void attn_step(const __bf16* __restrict__ kls,
                                          const __bf16* __restrict__ vls,
                                          int half, const bf16x8 (&qf)[4],
                                          int l31, int hi,
                                          float& mrun, float& lrun,
                                          f32x16& o0, f32x16& o1) {
  const int kr = half * 32 + l31;
  const int krx = kr & 7;

  f32x16 s;
  #pragma unroll
  for (int r = 0; r < 16; ++r) s[r] = 0.f;
  #pragma unroll
  for (int sl = 0; sl < 4; ++sl) {
    bf16x8 kf = *(const bf16x8*)&kls[(kr * 8 + ((2 * sl + hi) ^ krx)) * 8];
    s = __builtin_amdgcn_mfma_f32_32x32x16_bf16(kf, qf[sl], s, 0, 0, 0);
  }
  if (MASK) {
    #pragma unroll
    for (int r = 1; r < 16; ++r) s[r] = -1e30f;
    if (hi) s[0] = -1e30f;
  }

  const float mloc = pairmax(tree_max16(s));
  if (!__all(mloc - mrun <= 8.f)) {   // defer-max (T13)
    const float mnew = fmaxf(mrun, mloc);
    const float corr = EXP2F(mrun - mnew);
    lrun *= corr;
    #pragma unroll
    for (int r = 0; r < 16; ++r) { o0[r] *= corr; o1[r] *= corr; }
    mrun = mnew;
  }

  #pragma unroll
  for (int r = 0; r < 16; ++r) s[r] = EXP2F(s[r] - mrun);
  lrun += pairsum(tree_sum16(s));

  bf16x8 pa[2];
  build_pa(s, hi, pa);

  #pragma unroll
  for (int ot = 0; ot < 2; ++ot) {
    const int vr = ot * 32 + l31;
    const int vrx = vr & 7;
    f32x16& o = ot ? o1 : o0;
    #pragma unroll
    for (int j = 0; j < 2; ++j) {
      bf16x8 vf = *(const bf16x8*)&vls[(vr * 8 + ((half * 4 + 2 * j + hi) ^ vrx)) * 8];
      o = __builtin_amdgcn_mfma_f32_32x32x16_bf16(vf, pa[j], o, 0, 0, 0);
    }
  }
}

__global__ void __launch_bounds__(512, 4)
attn_kernel(const __bf16* __restrict__ qb, const __bf16* __restrict__ kb,
            const __bf16* __restrict__ vtb, __bf16* __restrict__ ao) {
  __shared__ __bf16 kls[2][64 * 64];
  __shared__ __bf16 vls[2][64 * 64];

  const int tid  = threadIdx.x;
  const int wid  = tid >> 6;
  const int lane = tid & 63;
  const int l31 = lane & 31, hi = (lane >> 5) & 1;

  const int bid = blockIdx.x;
  const int xcd = bid & 7;
  const int ixd = bid >> 3;
  const int bh  = xcd * (BHTOT / 8) + ixd / 5;
  const int qblk = ixd % 5;
  const int qt  = qblk * 8 + wid;
  const bool active = qt < QT32;

  const __bf16* Qp = qb + (size_t)bh * SEQ * HDIM;
  const __bf16* Kp = kb + (size_t)bh * SEQ * HDIM;
  const __bf16* Vp = vtb + (size_t)bh * HDIM * SPAD;

  const int qidx = qt * 32 + l31;
  const int qc = (qidx < SEQ ? qidx : SEQ - 1);
  bf16x8 qf[4];
  if (active) {
    #pragma unroll
    for (int sl = 0; sl < 4; ++sl)
      qf[sl] = *(const bf16x8*)&Qp[(size_t)qc * HDIM + sl * 16 + hi * 8];
  }

  f32x16 o0, o1;
  #pragma unroll
  for (int r = 0; r < 16; ++r) { o0[r] = 0.f; o1[r] = 0.f; }
  float mrun = -1e30f, lrun = 0.f;

  stage_kv(Kp, Vp, kls[0], vls[0], 0, tid);
  __syncthreads();

  for (int t = 0; t < NTILE; ++t) {
    const int cur = t & 1;
    if (t + 1 < NTILE)
      stage_kv(Kp, Vp, kls[cur ^ 1], vls[cur ^ 1], (t + 1) * 64, tid);
    if (active) {
      if (t < NTILE - 1) {
        attn_step<false>(kls[cur], vls[cur], 0, qf, l31, hi, mrun, lrun, o0, o1);
        attn_step<false>(kls[cur], vls[cur], 1, qf, l31, hi, mrun, lrun, o0, o1);
      } else {
        attn_step<true>(kls[cur], vls[cur], 0, qf, l31, hi, mrun, lrun, o0, o1);
      }
    }
    __syncthreads();
  }

  if (active && qidx < SEQ) {
    const int b = bh / NHEAD, h = bh % NHEAD;
    const float inv = 1.f / lrun;
    __bf16* base = ao + ((size_t)b * SEQ + qidx) * DMODEL + h * HDIM + hi * 4;
    #pragma unroll
    for (int t = 0; t < 2; ++t) {
      const f32x16& o = t ? o1 : o0;
      #pragma unroll
      for (int g = 0; g < 4; ++g) {
        bf16x4 w;
        #pragma unroll
        for (int u = 0; u < 4; ++u) w[u] = (__bf16)(o[g * 4 + u] * inv);
        *(bf16x4*)(base + t * 32 + g * 8) = w;
      }
    }
  }
}

// ---------------- launcher ----------------
extern "C" void kernel_launch(void* const* d_in, const int* in_sizes, int n_in,
                              void* d_out, int out_size, void* d_ws, size_t ws_size,
                              hipStream_t stream) {
  const float* x  = (const float*)d_in[0];
  const float* Wk = (const float*)d_in[1];
  const float* bk = (const float*)d_in[2];
  const float* Wq = (const float*)d_in[3];
  const float* bq = (const float*)d_in[4];
  const float* Wv = (const float*)d_in[5];
  const float* bv = (const float*)d_in[6];
  const float* Wp = (const float*)d_in[7];
  const float* bp = (const float*)d_in[8];
  float* out = (float*)d_out;

  if (ws_size < WS_NEEDED) return;

  char* ws = (char*)d_ws;
  __bf16* xb  = (__bf16*)(ws + XB_OFF);
  __bf16* wqb = (__bf16*)(ws + WQB_OFF);   // stacked Wq|Wk|Wv|Wp
  __bf16* wpb = (__bf16*)(ws + WPB_OFF);
  __bf16* qb  = (__bf16*)(ws + QB_OFF);
  __bf16* kb  = (__bf16*)(ws + KB_OFF);
  __bf16* vtb = (__bf16*)(ws + VT_OFF);
  __bf16* ab  = (__bf16*)(ws + AO_OFF);    // aliases xb

  // zero V^T (incl. padded tail columns 1025..1055 -> exact 0 * 0 in PV, no NaN;
  // also the region K-tail staging overruns into)
  hipMemsetAsync(vtb, 0, VT_SZ, stream);

  {
    const int n_src = MTOT * DMODEL, n_dst = MPAD * DMODEL;
    convert_f32_bf16<<<dim3((n_dst / 4 + 255) / 256), dim3(256), 0, stream>>>(x, xb, n_src, n_dst);
    const int nw = DMODEL * DMODEL;
    convert_w4<<<dim3((nw / 4 + 255) / 256, 4), dim3(256), 0, stream>>>(Wq, Wk, Wv, Wp, wqb);
  }

  // fused QKV GEMM: 65 m-blocks x 18 stacked-n-blocks = 1170
  gemm_qkv_kernel<<<dim3(1170), dim3(256), 0, stream>>>(
      xb, wqb, bq, bk, bv, qb, kb, vtb);

  attn_kernel<<<dim3(8 * (BHTOT / 8) * 5), dim3(512), 0, stream>>>(qb, kb, vtb, ab);

  // projection GEMM: 65 x 6 = 390
  gemm_proj_kernel<<<dim3(390), dim3(256), 0, stream>>>(ab, wpb, bp, out);
}